// Round 1
// 649.278 us; speedup vs baseline: 2.6638x; 2.6638x over previous
//
#include <hip/hip_runtime.h>
#include <math.h>

// Problem constants
#define BATCH 2
#define SEQ   2048
#define DM    768
#define NHD   12
#define NL    2
#define DFF   3072
#define DH    64
#define HW    256            // WIN // 2
#define MR    (BATCH*SEQ)    // 4096
#define EPSF  1e-5f
#define SCALE 0.125f         // DH^-0.5

typedef __attribute__((ext_vector_type(8))) __bf16 bf16x8;
typedef __attribute__((ext_vector_type(4))) float  f32x4;

__device__ __forceinline__ ushort f2bu(float f) {
    union { __bf16 h; ushort u; } c;
    c.h = (__bf16)f;
    return c.u;
}
__device__ __forceinline__ float bu2f(ushort u) {
    union { uint u; float f; } c;
    c.u = ((uint)u) << 16;
    return c.f;
}

// ---------------------------------------------------------------------------
// fp32 -> bf16 cast, 4 elems/thread (n divisible by 1024)
// ---------------------------------------------------------------------------
__global__ __launch_bounds__(256) void cvt(const float* __restrict__ in,
                                           ushort* __restrict__ out, int n)
{
    int i = (blockIdx.x * 256 + threadIdx.x) * 4;
    if (i >= n) return;
    float4 v = *(const float4*)(in + i);
    ushort4 o;
    o.x = f2bu(v.x); o.y = f2bu(v.y); o.z = f2bu(v.z); o.w = f2bu(v.w);
    *(ushort4*)(out + i) = o;
}

// ---------------------------------------------------------------------------
// MFMA GEMM: C[m,n] = A[m,:].W[n,:] + bias[n]  (opt ReLU), all operands bf16,
// bias fp32, C bf16. 256 thr = 4 waves; 64x64 tile; BK=32; wave = 32x32 via
// 2x2 mfma_f32_16x16x32_bf16.
// Fragment layouts (learn_hip m89/m91/m92, HW-verified):
//   A-frag: A[m = lane&15][k = (lane>>4)*8 + j]
//   B-frag: W[n = lane&15][k = (lane>>4)*8 + j]
//   C/D:    col(n) = lane&15, row(m) = (lane>>4)*4 + reg
// ---------------------------------------------------------------------------
#define BKP 40   // LDS pitch in bf16 (80 B rows: 16B-aligned, 2-way-max conflicts)

__global__ __launch_bounds__(256) void gemm_bf16(
    const ushort* __restrict__ A, const ushort* __restrict__ W,
    const float* __restrict__ bias, ushort* __restrict__ C,
    int M, int N, int K, int relu)
{
    __shared__ ushort As[64][BKP];
    __shared__ ushort Ws[64][BKP];

    const int t  = threadIdx.x;
    const int bm = blockIdx.y * 64;
    const int bn = blockIdx.x * 64;

    const int w    = t >> 6;
    const int wm   = (w >> 1) * 32;
    const int wn   = (w & 1) * 32;
    const int lane = t & 63;
    const int quad = lane >> 4;
    const int lrow = lane & 15;

    const int srow = t >> 2;           // 0..63
    const int skc  = (t & 3) * 8;      // 0,8,16,24

    const ushort* ap = A + (size_t)(bm + srow) * K + skc;
    const ushort* wp = W + (size_t)(bn + srow) * K + skc;

    f32x4 acc[2][2] = {};

    for (int k0 = 0; k0 < K; k0 += 32) {
        uint4 av = *(const uint4*)(ap + k0);
        uint4 wv = *(const uint4*)(wp + k0);
        *(uint4*)&As[srow][skc] = av;
        *(uint4*)&Ws[srow][skc] = wv;
        __syncthreads();

        bf16x8 af[2], bf[2];
#pragma unroll
        for (int i = 0; i < 2; ++i)
            af[i] = *(const bf16x8*)&As[wm + i * 16 + lrow][quad * 8];
#pragma unroll
        for (int j = 0; j < 2; ++j)
            bf[j] = *(const bf16x8*)&Ws[wn + j * 16 + lrow][quad * 8];

#pragma unroll
        for (int i = 0; i < 2; ++i)
#pragma unroll
            for (int j = 0; j < 2; ++j)
                acc[i][j] = __builtin_amdgcn_mfma_f32_16x16x32_bf16(
                    af[i], bf[j], acc[i][j], 0, 0, 0);
        __syncthreads();
    }

#pragma unroll
    for (int j = 0; j < 2; ++j) {
        const int col = bn + wn + j * 16 + lrow;
        const float bv = bias[col];
#pragma unroll
        for (int i = 0; i < 2; ++i) {
            const int rbase = bm + wm + i * 16 + quad * 4;
#pragma unroll
            for (int r = 0; r < 4; ++r) {
                float v = acc[i][j][r] + bv;
                if (relu) v = fmaxf(v, 0.f);
                C[(size_t)(rbase + r) * N + col] = f2bu(v);
            }
        }
    }
}

// ---------------------------------------------------------------------------
// Banded attention, MFMA version. Block = (32 queries, head, batch), 256 thr
// = 4 waves. bf16 I/O, fp32 MFMA accum. Union key window for 32 queries:
// [i0-256, i0+31+256] -> 9 chunks of 64 keys.
//   Pass 1 (QK^T): per chunk, wave w computes q-tile (w>>1)*16, k-tiles
//     (w&1)*32 + {0,16}; scores masked+scaled, stored bf16 in sc[32][584].
//   Softmax: 8 lanes/row shuffle reduce; P=exp(s-mx) stored bf16 in-place.
//   Pass 2 (P.V): V chunk stored TRANSPOSED in LDS (vt[dh][key]) with XOR
//     block swizzle blk=(jj>>3)^(dh>>3) so the transpose scatter writes are
//     bank-conflict-free while B-fragments stay contiguous ds_read_b128.
// ---------------------------------------------------------------------------
#define QT  32
#define NCH 9    // 9*64 = 576 >= 32+512
#define KP  72   // kv/qs pitch in bf16 (144 B rows: 16B-aligned, 2-way max)
#define SCP 584  // score pitch in bf16 (1168 B rows: 16B-aligned, 2-way max)

__global__ __launch_bounds__(256) void attn(
    const ushort* __restrict__ q, const ushort* __restrict__ k,
    const ushort* __restrict__ v, ushort* __restrict__ o)
{
    __shared__ ushort qs[QT][KP];
    __shared__ ushort kv[64][KP];
    __shared__ ushort sc[QT][SCP];
    __shared__ float  rinv[QT];

    const int t    = threadIdx.x;
    const int i0   = blockIdx.x * QT;
    const int h    = blockIdx.y;
    const int b    = blockIdx.z;
    const size_t base = (size_t)b * SEQ * DM + (size_t)h * DH;

    const int w    = t >> 6;
    const int lane = t & 63;
    const int quad = lane >> 4;
    const int lrow = lane & 15;
    const int qrow = (w >> 1) * 16;     // wave's 16-query sub-tile

    // ---- stage Q: 32 rows x 64 dh, one uint4 per thread -------------------
    {
        int qi = t >> 3, d0 = (t & 7) * 8;
        uint4 raw = *(const uint4*)(q + base + (size_t)(i0 + qi) * DM + d0);
        *(uint4*)&qs[qi][d0] = raw;
    }
    __syncthreads();

    // Q fragments are chunk-invariant: hoist.
    const bf16x8 a0 = *(const bf16x8*)&qs[qrow + lrow][quad * 8];
    const bf16x8 a1 = *(const bf16x8*)&qs[qrow + lrow][32 + quad * 8];

    const int jstart = i0 - HW;

    // ---- pass 1: QK^T into sc (bf16), masked + scaled ---------------------
    for (int c = 0; c < NCH; ++c) {
        const int j0 = jstart + c * 64;
#pragma unroll
        for (int e = 0; e < 2; ++e) {
            int idx = t + 256 * e;
            int jj = idx >> 3, d0 = (idx & 7) * 8;
            int j = j0 + jj;
            uint4 raw = make_uint4(0, 0, 0, 0);
            if (j >= 0 && j < SEQ)
                raw = *(const uint4*)(k + base + (size_t)j * DM + d0);
            *(uint4*)&kv[jj][d0] = raw;
        }
        __syncthreads();

#pragma unroll
        for (int kt = 0; kt < 2; ++kt) {
            const int krow = (w & 1) * 32 + kt * 16;
            bf16x8 b0 = *(const bf16x8*)&kv[krow + lrow][quad * 8];
            bf16x8 b1 = *(const bf16x8*)&kv[krow + lrow][32 + quad * 8];
            f32x4 acc = {};
            acc = __builtin_amdgcn_mfma_f32_16x16x32_bf16(a0, b0, acc, 0, 0, 0);
            acc = __builtin_amdgcn_mfma_f32_16x16x32_bf16(a1, b1, acc, 0, 0, 0);
            const int jg = j0 + krow + lrow;
#pragma unroll
            for (int r = 0; r < 4; ++r) {
                const int qi = qrow + quad * 4 + r;
                const int ig = i0 + qi;
                bool ok = (jg >= 0) && (jg < SEQ) &&
                          (jg >= ig - HW) && (jg <= ig + HW);
                float s = ok ? acc[r] * SCALE : -1e30f;
                sc[qi][c * 64 + krow + lrow] = f2bu(s);
            }
        }
        __syncthreads();
    }

    // ---- softmax: 8 lanes per row -----------------------------------------
    {
        const int r = t >> 3, l8 = t & 7;
        float mx = -1e30f;
        for (int cix = l8; cix < NCH * 64; cix += 8)
            mx = fmaxf(mx, bu2f(sc[r][cix]));
#pragma unroll
        for (int off = 4; off; off >>= 1) mx = fmaxf(mx, __shfl_xor(mx, off));
        float sum = 0.f;
        for (int cix = l8; cix < NCH * 64; cix += 8) {
            float e = __expf(bu2f(sc[r][cix]) - mx);
            sc[r][cix] = f2bu(e);
            sum += e;
        }
#pragma unroll
        for (int off = 4; off; off >>= 1) sum += __shfl_xor(sum, off);
        if (l8 == 0) rinv[r] = 1.f / sum;
    }
    __syncthreads();

    // ---- pass 2: O = P.V ---------------------------------------------------
    f32x4 oacc[2] = {};
    const int nbase = (w & 1) * 32;     // wave's 32-wide dh sub-tile

    for (int c = 0; c < NCH; ++c) {
        const int j0 = jstart + c * 64;
#pragma unroll
        for (int e = 0; e < 2; ++e) {
            int idx = t + 256 * e;
            int jj = idx >> 3, d0 = (idx & 7) * 8;
            int j = j0 + jj;
            uint4 raw = make_uint4(0, 0, 0, 0);
            if (j >= 0 && j < SEQ)
                raw = *(const uint4*)(v + base + (size_t)j * DM + d0);
            const ushort* u = (const ushort*)&raw;
            // transposed, XOR-swizzled store: vt[dh][key]
#pragma unroll
            for (int x = 0; x < 8; ++x) {
                int dh  = d0 + x;
                int blk = ((jj >> 3) ^ (dh >> 3)) & 7;
                kv[dh][blk * 8 + (jj & 7)] = u[x];
            }
        }
        __syncthreads();

        bf16x8 pa0 = *(const bf16x8*)&sc[qrow + lrow][c * 64 + quad * 8];
        bf16x8 pa1 = *(const bf16x8*)&sc[qrow + lrow][c * 64 + 32 + quad * 8];
#pragma unroll
        for (int nt = 0; nt < 2; ++nt) {
            const int dh  = nbase + nt * 16 + lrow;
            const int rsw = (dh >> 3) & 7;
            bf16x8 b0 = *(const bf16x8*)&kv[dh][((quad)     ^ rsw) * 8];
            bf16x8 b1 = *(const bf16x8*)&kv[dh][((quad + 4) ^ rsw) * 8];
            oacc[nt] = __builtin_amdgcn_mfma_f32_16x16x32_bf16(pa0, b0, oacc[nt], 0, 0, 0);
            oacc[nt] = __builtin_amdgcn_mfma_f32_16x16x32_bf16(pa1, b1, oacc[nt], 0, 0, 0);
        }
        __syncthreads();
    }

    // ---- write O: col(dh) = lane&15, row(q) = quad*4 + r ------------------
#pragma unroll
    for (int nt = 0; nt < 2; ++nt) {
        const int dcol = nbase + nt * 16 + lrow;
#pragma unroll
        for (int r = 0; r < 4; ++r) {
            const int qi = qrow + quad * 4 + r;
            o[base + (size_t)(i0 + qi) * DM + dcol] = f2bu(oacc[nt][r] * rinv[qi]);
        }
    }
}

// ---------------------------------------------------------------------------
// Residual + LayerNorm, one wave per row. bf16 in; bf16 out or fp32 (final).
// ---------------------------------------------------------------------------
__global__ __launch_bounds__(64) void add_ln(
    const ushort* __restrict__ xa, const ushort* __restrict__ yb,
    const float* __restrict__ g, const float* __restrict__ be,
    ushort* __restrict__ ob, float* __restrict__ of, int fin)
{
    const int r = blockIdx.x, t = threadIdx.x;
    const size_t off = (size_t)r * DM;
    float sv[12];
    float s1 = 0.f, s2 = 0.f;
#pragma unroll
    for (int ii = 0; ii < 12; ++ii) {
        float vv = bu2f(xa[off + t + 64 * ii]) + bu2f(yb[off + t + 64 * ii]);
        sv[ii] = vv; s1 += vv; s2 += vv * vv;
    }
#pragma unroll
    for (int o2 = 32; o2; o2 >>= 1) {
        s1 += __shfl_xor(s1, o2);
        s2 += __shfl_xor(s2, o2);
    }
    const float mean = s1 * (1.f / 768.f);
    const float rstd = rsqrtf(s2 * (1.f / 768.f) - mean * mean + EPSF);
#pragma unroll
    for (int ii = 0; ii < 12; ++ii) {
        const int c = t + 64 * ii;
        float v = (sv[ii] - mean) * rstd * g[c] + be[c];
        if (fin) of[off + c] = v;
        else     ob[off + c] = f2bu(v);
    }
}

// ---------------------------------------------------------------------------
// Host orchestration. ws (bf16 elems): weights 14.16M + activations 37.7M
// = 51.9M elems ~= 104 MB (R5 proved 113 MB works).
// ---------------------------------------------------------------------------
extern "C" void kernel_launch(void* const* d_in, const int* in_sizes, int n_in,
                              void* d_out, int out_size, void* d_ws, size_t ws_size,
                              hipStream_t stream) {
    (void)in_sizes; (void)n_in; (void)out_size; (void)ws_size;
    const float* src = (const float*)d_in[0];
    const float* qw  = (const float*)d_in[1];
    const float* qb  = (const float*)d_in[2];
    const float* kw  = (const float*)d_in[3];
    const float* kb  = (const float*)d_in[4];
    const float* vw  = (const float*)d_in[5];
    const float* vb  = (const float*)d_in[6];
    const float* ow  = (const float*)d_in[7];
    const float* ob  = (const float*)d_in[8];
    const float* w1  = (const float*)d_in[9];
    const float* b1  = (const float*)d_in[10];
    const float* w2  = (const float*)d_in[11];
    const float* b2  = (const float*)d_in[12];
    const float* g1  = (const float*)d_in[13];
    const float* be1 = (const float*)d_in[14];
    const float* g2  = (const float*)d_in[15];
    const float* be2 = (const float*)d_in[16];

    const size_t A   = (size_t)MR * DM;        // 3,145,728
    const size_t WD  = (size_t)NL * DM * DM;   // 1,179,648
    const size_t WF  = (size_t)NL * DFF * DM;  // 4,718,592

    ushort* p = (ushort*)d_ws;
    ushort* qwB = p; p += WD;
    ushort* kwB = p; p += WD;
    ushort* vwB = p; p += WD;
    ushort* owB = p; p += WD;
    ushort* w1B = p; p += WF;
    ushort* w2B = p; p += WF;
    ushort* xb  = p; p += A;
    ushort* qB  = p; p += A;
    ushort* kB  = p; p += A;
    ushort* vB  = p; p += A;
    ushort* oB  = p; p += A;
    ushort* yB  = p; p += A;
    ushort* h1  = p; p += A;
    ushort* y2  = p; p += A;
    ushort* ffh = p;                            // MR*DFF = 12.58M elems

    // weight + src conversion (all sizes divisible by 1024)
    cvt<<<(int)(WD / 1024), 256, 0, stream>>>(qw, qwB, (int)WD);
    cvt<<<(int)(WD / 1024), 256, 0, stream>>>(kw, kwB, (int)WD);
    cvt<<<(int)(WD / 1024), 256, 0, stream>>>(vw, vwB, (int)WD);
    cvt<<<(int)(WD / 1024), 256, 0, stream>>>(ow, owB, (int)WD);
    cvt<<<(int)(WF / 1024), 256, 0, stream>>>(w1, w1B, (int)WF);
    cvt<<<(int)(WF / 1024), 256, 0, stream>>>(w2, w2B, (int)WF);
    cvt<<<(int)(A  / 1024), 256, 0, stream>>>(src, xb, (int)A);

    const dim3 gP(DM / 64, MR / 64);    // (12, 64)
    const dim3 gF1(DFF / 64, MR / 64);  // (48, 64)
    const dim3 gA(SEQ / QT, NHD, BATCH);  // (64, 12, 2)

    for (int l = 0; l < NL; ++l) {
        const size_t wD = (size_t)l * DM * DM;
        const size_t wF = (size_t)l * DFF * DM;
        const size_t bD = (size_t)l * DM;   // (L, DM) tensors — incl. b2!
        const size_t bF = (size_t)l * DFF;  // (L, DFF) tensors

        gemm_bf16<<<gP, 256, 0, stream>>>(xb, qwB + wD, qb + bD, qB,
                                          MR, DM, DM, 0);
        gemm_bf16<<<gP, 256, 0, stream>>>(xb, kwB + wD, kb + bD, kB,
                                          MR, DM, DM, 0);
        gemm_bf16<<<gP, 256, 0, stream>>>(xb, vwB + wD, vb + bD, vB,
                                          MR, DM, DM, 0);
        attn<<<gA, 256, 0, stream>>>(qB, kB, vB, oB);
        gemm_bf16<<<gP, 256, 0, stream>>>(oB, owB + wD, ob + bD, yB,
                                          MR, DM, DM, 0);
        add_ln<<<MR, 64, 0, stream>>>(xb, yB, g1 + bD, be1 + bD,
                                      h1, nullptr, 0);
        gemm_bf16<<<gF1, 256, 0, stream>>>(h1, w1B + wF, b1 + bF, ffh,
                                           MR, DFF, DM, 1);
        gemm_bf16<<<gP, 256, 0, stream>>>(ffh, w2B + wF, b2 + bD, xb,
                                          MR, DM, DFF, 0);
        if (l == NL - 1)
            add_ln<<<MR, 64, 0, stream>>>(h1, xb, g2 + bD, be2 + bD,
                                          nullptr, (float*)d_out, 1);
        else
            add_ln<<<MR, 64, 0, stream>>>(h1, xb, g2 + bD, be2 + bD,
                                          xb, nullptr, 0);
    }
}

// Round 2
// 622.327 us; speedup vs baseline: 2.7792x; 1.0433x over previous
//
#include <hip/hip_runtime.h>
#include <math.h>

// Problem constants
#define BATCH 2
#define SEQ   2048
#define DM    768
#define NHD   12
#define NL    2
#define DFF   3072
#define DH    64
#define HW    256            // WIN // 2
#define MR    (BATCH*SEQ)    // 4096
#define EPSF  1e-5f
#define SCALE 0.125f         // DH^-0.5
#define QKVS  2304           // fused qkv activation row stride

typedef __attribute__((ext_vector_type(8))) __bf16 bf16x8;
typedef __attribute__((ext_vector_type(4))) float  f32x4;

__device__ __forceinline__ ushort f2bu(float f) {
    union { __bf16 h; ushort u; } c;
    c.h = (__bf16)f;
    return c.u;
}
__device__ __forceinline__ float bu2f(ushort u) {
    union { uint u; float f; } c;
    c.u = ((uint)u) << 16;
    return c.f;
}

// async global->LDS, 16B per lane. LDS dest must be linear: uniform base +
// lane*16 within each wave (learn_hip m104). We pass the per-lane address
// that satisfies exactly that.
__device__ __forceinline__ void gload16(const ushort* g, ushort* l) {
    __builtin_amdgcn_global_load_lds(
        (const __attribute__((address_space(1))) void*)g,
        (__attribute__((address_space(3))) void*)l, 16, 0, 0);
}

// ---------------------------------------------------------------------------
// fp32 -> bf16 cast, 4 elems/thread (n divisible by 1024)
// ---------------------------------------------------------------------------
__global__ __launch_bounds__(256) void cvt(const float* __restrict__ in,
                                           ushort* __restrict__ out, int n)
{
    int i = (blockIdx.x * 256 + threadIdx.x) * 4;
    if (i >= n) return;
    float4 v = *(const float4*)(in + i);
    ushort4 o;
    o.x = f2bu(v.x); o.y = f2bu(v.y); o.z = f2bu(v.z); o.w = f2bu(v.w);
    *(ushort4*)(out + i) = o;
}

// ---------------------------------------------------------------------------
// MFMA GEMM, m97 structure: 128x128 tile, BK=32, 256 thr = 4 waves (2x2),
// each wave computes 64x64 via 4x4 mfma_f32_16x16x32_bf16 fragments.
// Staging: global_load_lds width=16, linear LDS [128][32] (no pad -- m104).
// Fragment layouts (learn_hip m89/m91, HW-verified):
//   A-frag: A[m = lane&15][k = (lane>>4)*8 + j]
//   B-frag: W[n = lane&15][k = (lane>>4)*8 + j]
//   C/D:    col(n) = lane&15, row(m) = (lane>>4)*4 + reg
// ---------------------------------------------------------------------------
__global__ __launch_bounds__(256) void gemm128(
    const ushort* __restrict__ A, const ushort* __restrict__ W,
    const float* __restrict__ bias, ushort* __restrict__ C,
    int M, int N, int K, int relu)
{
    __shared__ ushort As[128 * 32];
    __shared__ ushort Ws[128 * 32];

    const int t  = threadIdx.x;
    const int bm = blockIdx.y * 128;
    const int bn = blockIdx.x * 128;

    const int w    = t >> 6;
    const int lane = t & 63;
    const int quad = lane >> 4;
    const int lrow = lane & 15;
    const int wm   = (w >> 1) * 64;
    const int wn   = (w & 1) * 64;

    // staging map: elem = (e*256 + t)*8 ; row = elem/32, col = elem%32
    const int srow = t >> 2;          // 0..63 (e=0), +64 for e=1
    const int scol = (t & 3) * 8;
    const ushort* ag = A + (size_t)(bm + srow) * K + scol;
    const ushort* wg = W + (size_t)(bn + srow) * K + scol;
    ushort* la0 = &As[t * 8];
    ushort* la1 = &As[2048 + t * 8];
    ushort* lw0 = &Ws[t * 8];
    ushort* lw1 = &Ws[2048 + t * 8];

    f32x4 acc[4][4] = {};

    for (int k0 = 0; k0 < K; k0 += 32) {
        gload16(ag + k0,                  la0);
        gload16(ag + (size_t)64 * K + k0, la1);
        gload16(wg + k0,                  lw0);
        gload16(wg + (size_t)64 * K + k0, lw1);
        __syncthreads();   // compiler drains vmcnt before s_barrier

        bf16x8 af[4], bfr[4];
#pragma unroll
        for (int i = 0; i < 4; ++i)
            af[i] = *(const bf16x8*)&As[(wm + i * 16 + lrow) * 32 + quad * 8];
#pragma unroll
        for (int j = 0; j < 4; ++j)
            bfr[j] = *(const bf16x8*)&Ws[(wn + j * 16 + lrow) * 32 + quad * 8];

#pragma unroll
        for (int i = 0; i < 4; ++i)
#pragma unroll
            for (int j = 0; j < 4; ++j)
                acc[i][j] = __builtin_amdgcn_mfma_f32_16x16x32_bf16(
                    af[i], bfr[j], acc[i][j], 0, 0, 0);
        __syncthreads();
    }

#pragma unroll
    for (int j = 0; j < 4; ++j) {
        const int col = bn + wn + j * 16 + lrow;
        const float bv = bias[col];
#pragma unroll
        for (int i = 0; i < 4; ++i) {
            const int rb = bm + wm + i * 16 + quad * 4;
#pragma unroll
            for (int r = 0; r < 4; ++r) {
                float vv = acc[i][j][r] + bv;
                if (relu) vv = fmaxf(vv, 0.f);
                C[(size_t)(rb + r) * N + col] = f2bu(vv);
            }
        }
    }
}

// ---------------------------------------------------------------------------
// Banded attention, MFMA version. Block = (32 queries, head, batch), 256 thr
// = 4 waves. q/k/v come from the fused QKV buffer (row stride QKVS); o is
// written at DM stride. Union key window: 9 chunks of 64 keys.
// ---------------------------------------------------------------------------
#define QT  32
#define NCH 9    // 9*64 = 576 >= 32+512
#define KP  72   // kv/qs pitch in bf16 (144 B rows: 16B-aligned, 2-way max)
#define SCP 584  // score pitch in bf16 (1168 B rows: 16B-aligned, 2-way max)

__global__ __launch_bounds__(256) void attn(
    const ushort* __restrict__ q, const ushort* __restrict__ k,
    const ushort* __restrict__ v, ushort* __restrict__ o)
{
    __shared__ ushort qs[QT][KP];
    __shared__ ushort kv[64][KP];
    __shared__ ushort sc[QT][SCP];
    __shared__ float  rinv[QT];

    const int t    = threadIdx.x;
    const int i0   = blockIdx.x * QT;
    const int h    = blockIdx.y;
    const int b    = blockIdx.z;
    const size_t ibase = (size_t)b * SEQ * QKVS + (size_t)h * DH;  // q/k/v
    const size_t obase = (size_t)b * SEQ * DM   + (size_t)h * DH;  // o

    const int w    = t >> 6;
    const int lane = t & 63;
    const int quad = lane >> 4;
    const int lrow = lane & 15;
    const int qrow = (w >> 1) * 16;     // wave's 16-query sub-tile

    // ---- stage Q: 32 rows x 64 dh, one uint4 per thread -------------------
    {
        int qi = t >> 3, d0 = (t & 7) * 8;
        uint4 raw = *(const uint4*)(q + ibase + (size_t)(i0 + qi) * QKVS + d0);
        *(uint4*)&qs[qi][d0] = raw;
    }
    __syncthreads();

    // Q fragments are chunk-invariant: hoist.
    const bf16x8 a0 = *(const bf16x8*)&qs[qrow + lrow][quad * 8];
    const bf16x8 a1 = *(const bf16x8*)&qs[qrow + lrow][32 + quad * 8];

    const int jstart = i0 - HW;

    // ---- pass 1: QK^T into sc (bf16), masked + scaled ---------------------
    for (int c = 0; c < NCH; ++c) {
        const int j0 = jstart + c * 64;
#pragma unroll
        for (int e = 0; e < 2; ++e) {
            int idx = t + 256 * e;
            int jj = idx >> 3, d0 = (idx & 7) * 8;
            int j = j0 + jj;
            uint4 raw = make_uint4(0, 0, 0, 0);
            if (j >= 0 && j < SEQ)
                raw = *(const uint4*)(k + ibase + (size_t)j * QKVS + d0);
            *(uint4*)&kv[jj][d0] = raw;
        }
        __syncthreads();

#pragma unroll
        for (int kt = 0; kt < 2; ++kt) {
            const int krow = (w & 1) * 32 + kt * 16;
            bf16x8 b0 = *(const bf16x8*)&kv[krow + lrow][quad * 8];
            bf16x8 b1 = *(const bf16x8*)&kv[krow + lrow][32 + quad * 8];
            f32x4 acc = {};
            acc = __builtin_amdgcn_mfma_f32_16x16x32_bf16(a0, b0, acc, 0, 0, 0);
            acc = __builtin_amdgcn_mfma_f32_16x16x32_bf16(a1, b1, acc, 0, 0, 0);
            const int jg = j0 + krow + lrow;
#pragma unroll
            for (int r = 0; r < 4; ++r) {
                const int qi = qrow + quad * 4 + r;
                const int ig = i0 + qi;
                bool ok = (jg >= 0) && (jg < SEQ) &&
                          (jg >= ig - HW) && (jg <= ig + HW);
                float s = ok ? acc[r] * SCALE : -1e30f;
                sc[qi][c * 64 + krow + lrow] = f2bu(s);
            }
        }
        __syncthreads();
    }

    // ---- softmax: 8 lanes per row -----------------------------------------
    {
        const int r = t >> 3, l8 = t & 7;
        float mx = -1e30f;
        for (int cix = l8; cix < NCH * 64; cix += 8)
            mx = fmaxf(mx, bu2f(sc[r][cix]));
#pragma unroll
        for (int off = 4; off; off >>= 1) mx = fmaxf(mx, __shfl_xor(mx, off));
        float sum = 0.f;
        for (int cix = l8; cix < NCH * 64; cix += 8) {
            float e = __expf(bu2f(sc[r][cix]) - mx);
            sc[r][cix] = f2bu(e);
            sum += e;
        }
#pragma unroll
        for (int off = 4; off; off >>= 1) sum += __shfl_xor(sum, off);
        if (l8 == 0) rinv[r] = 1.f / sum;
    }
    __syncthreads();

    // ---- pass 2: O = P.V ---------------------------------------------------
    f32x4 oacc[2] = {};
    const int nbase = (w & 1) * 32;     // wave's 32-wide dh sub-tile

    for (int c = 0; c < NCH; ++c) {
        const int j0 = jstart + c * 64;
#pragma unroll
        for (int e = 0; e < 2; ++e) {
            int idx = t + 256 * e;
            int jj = idx >> 3, d0 = (idx & 7) * 8;
            int j = j0 + jj;
            uint4 raw = make_uint4(0, 0, 0, 0);
            if (j >= 0 && j < SEQ)
                raw = *(const uint4*)(v + ibase + (size_t)j * QKVS + d0);
            const ushort* u = (const ushort*)&raw;
            // transposed, XOR-swizzled store: vt[dh][key]
#pragma unroll
            for (int x = 0; x < 8; ++x) {
                int dh  = d0 + x;
                int blk = ((jj >> 3) ^ (dh >> 3)) & 7;
                kv[dh][blk * 8 + (jj & 7)] = u[x];
            }
        }
        __syncthreads();

        bf16x8 pa0 = *(const bf16x8*)&sc[qrow + lrow][c * 64 + quad * 8];
        bf16x8 pa1 = *(const bf16x8*)&sc[qrow + lrow][c * 64 + 32 + quad * 8];
#pragma unroll
        for (int nt = 0; nt < 2; ++nt) {
            const int dh  = nbase + nt * 16 + lrow;
            const int rsw = (dh >> 3) & 7;
            bf16x8 b0 = *(const bf16x8*)&kv[dh][((quad)     ^ rsw) * 8];
            bf16x8 b1 = *(const bf16x8*)&kv[dh][((quad + 4) ^ rsw) * 8];
            oacc[nt] = __builtin_amdgcn_mfma_f32_16x16x32_bf16(pa0, b0, oacc[nt], 0, 0, 0);
            oacc[nt] = __builtin_amdgcn_mfma_f32_16x16x32_bf16(pa1, b1, oacc[nt], 0, 0, 0);
        }
        __syncthreads();
    }

    // ---- write O: col(dh) = lane&15, row(q) = quad*4 + r ------------------
#pragma unroll
    for (int nt = 0; nt < 2; ++nt) {
        const int dcol = nbase + nt * 16 + lrow;
#pragma unroll
        for (int r = 0; r < 4; ++r) {
            const int qi = qrow + quad * 4 + r;
            o[obase + (size_t)(i0 + qi) * DM + dcol] = f2bu(oacc[nt][r] * rinv[qi]);
        }
    }
}

// ---------------------------------------------------------------------------
// Residual + LayerNorm, one wave per row. bf16 in; bf16 out or fp32 (final).
// ---------------------------------------------------------------------------
__global__ __launch_bounds__(64) void add_ln(
    const ushort* __restrict__ xa, const ushort* __restrict__ yb,
    const float* __restrict__ g, const float* __restrict__ be,
    ushort* __restrict__ ob, float* __restrict__ of, int fin)
{
    const int r = blockIdx.x, t = threadIdx.x;
    const size_t off = (size_t)r * DM;
    float sv[12];
    float s1 = 0.f, s2 = 0.f;
#pragma unroll
    for (int ii = 0; ii < 12; ++ii) {
        float vv = bu2f(xa[off + t + 64 * ii]) + bu2f(yb[off + t + 64 * ii]);
        sv[ii] = vv; s1 += vv; s2 += vv * vv;
    }
#pragma unroll
    for (int o2 = 32; o2; o2 >>= 1) {
        s1 += __shfl_xor(s1, o2);
        s2 += __shfl_xor(s2, o2);
    }
    const float mean = s1 * (1.f / 768.f);
    const float rstd = rsqrtf(s2 * (1.f / 768.f) - mean * mean + EPSF);
#pragma unroll
    for (int ii = 0; ii < 12; ++ii) {
        const int c = t + 64 * ii;
        float v = (sv[ii] - mean) * rstd * g[c] + be[c];
        if (fin) of[off + c] = v;
        else     ob[off + c] = f2bu(v);
    }
}

// ---------------------------------------------------------------------------
// Host orchestration.
// Workspace: 18KB fp32 bias-concat + ~97.5 MB bf16 (fits proven 113 MB).
// ---------------------------------------------------------------------------
extern "C" void kernel_launch(void* const* d_in, const int* in_sizes, int n_in,
                              void* d_out, int out_size, void* d_ws, size_t ws_size,
                              hipStream_t stream) {
    (void)in_sizes; (void)n_in; (void)out_size; (void)ws_size;
    const float* src = (const float*)d_in[0];
    const float* qw  = (const float*)d_in[1];
    const float* qb  = (const float*)d_in[2];
    const float* kw  = (const float*)d_in[3];
    const float* kb  = (const float*)d_in[4];
    const float* vw  = (const float*)d_in[5];
    const float* vb  = (const float*)d_in[6];
    const float* ow  = (const float*)d_in[7];
    const float* ob  = (const float*)d_in[8];
    const float* w1  = (const float*)d_in[9];
    const float* b1  = (const float*)d_in[10];
    const float* w2  = (const float*)d_in[11];
    const float* b2  = (const float*)d_in[12];
    const float* g1  = (const float*)d_in[13];
    const float* be1 = (const float*)d_in[14];
    const float* g2  = (const float*)d_in[15];
    const float* be2 = (const float*)d_in[16];

    const size_t A    = (size_t)MR * DM;         // 3,145,728
    const size_t WD1  = (size_t)DM * DM;         // 589,824  (per layer)
    const size_t WQKV = (size_t)3 * DM * DM;     // 1,769,472 (per layer)
    const size_t WF1  = (size_t)DFF * DM;        // 2,359,296 (per layer)
    const size_t WF   = (size_t)NL * WF1;        // 4,718,592

    float*  bcat = (float*)d_ws;                 // NL * 2304 fp32
    ushort* p    = (ushort*)(bcat + (size_t)NL * QKVS);
    ushort* qkvwB = p; p += (size_t)NL * WQKV;
    ushort* owB   = p; p += (size_t)NL * WD1;
    ushort* w1B   = p; p += WF;
    ushort* w2B   = p; p += WF;
    ushort* xb    = p; p += A;
    ushort* qkvB  = p; p += 3 * A;
    ushort* oB    = p; p += A;
    ushort* yB    = p; p += A;
    ushort* h1    = p; p += A;
    ushort* ffh   = p;                            // MR*DFF = 12.58M elems

    // bias concat (device-to-device, async on stream — graph-capture safe)
    for (int l = 0; l < NL; ++l) {
        hipMemcpyAsync(bcat + (size_t)l * QKVS + 0,    qb + (size_t)l * DM,
                       DM * sizeof(float), hipMemcpyDeviceToDevice, stream);
        hipMemcpyAsync(bcat + (size_t)l * QKVS + DM,   kb + (size_t)l * DM,
                       DM * sizeof(float), hipMemcpyDeviceToDevice, stream);
        hipMemcpyAsync(bcat + (size_t)l * QKVS + 2*DM, vb + (size_t)l * DM,
                       DM * sizeof(float), hipMemcpyDeviceToDevice, stream);
    }

    // weight + src conversion (all sizes divisible by 1024)
    for (int l = 0; l < NL; ++l) {
        cvt<<<(int)(WD1 / 1024), 256, 0, stream>>>(
            qw + (size_t)l * WD1, qkvwB + (size_t)l * WQKV + 0,     (int)WD1);
        cvt<<<(int)(WD1 / 1024), 256, 0, stream>>>(
            kw + (size_t)l * WD1, qkvwB + (size_t)l * WQKV + WD1,   (int)WD1);
        cvt<<<(int)(WD1 / 1024), 256, 0, stream>>>(
            vw + (size_t)l * WD1, qkvwB + (size_t)l * WQKV + 2*WD1, (int)WD1);
    }
    cvt<<<(int)(NL * WD1 / 1024), 256, 0, stream>>>(ow, owB, (int)(NL * WD1));
    cvt<<<(int)(WF / 1024), 256, 0, stream>>>(w1, w1B, (int)WF);
    cvt<<<(int)(WF / 1024), 256, 0, stream>>>(w2, w2B, (int)WF);
    cvt<<<(int)(A  / 1024), 256, 0, stream>>>(src, xb, (int)A);

    const dim3 gQKV(QKVS / 128, MR / 128);  // (18, 32)
    const dim3 gO(DM / 128, MR / 128);      // (6, 32)
    const dim3 gF1(DFF / 128, MR / 128);    // (24, 32)
    const dim3 gA(SEQ / QT, NHD, BATCH);    // (64, 12, 2)

    for (int l = 0; l < NL; ++l) {
        const size_t bD = (size_t)l * DM;
        const size_t bF = (size_t)l * DFF;

        gemm128<<<gQKV, 256, 0, stream>>>(xb, qkvwB + (size_t)l * WQKV,
                                          bcat + (size_t)l * QKVS, qkvB,
                                          MR, QKVS, DM, 0);
        attn<<<gA, 256, 0, stream>>>(qkvB, qkvB + DM, qkvB + 2 * DM, oB);
        gemm128<<<gO, 256, 0, stream>>>(oB, owB + (size_t)l * WD1, ob + bD, yB,
                                        MR, DM, DM, 0);
        add_ln<<<MR, 64, 0, stream>>>(xb, yB, g1 + bD, be1 + bD,
                                      h1, nullptr, 0);
        gemm128<<<gF1, 256, 0, stream>>>(h1, w1B + (size_t)l * WF1, b1 + bF, ffh,
                                         MR, DFF, DM, 1);
        gemm128<<<gO, 256, 0, stream>>>(ffh, w2B + (size_t)l * WF1, b2 + bD, xb,
                                        MR, DM, DFF, 0);
        if (l == NL - 1)
            add_ln<<<MR, 64, 0, stream>>>(h1, xb, g2 + bD, be2 + bD,
                                          nullptr, (float*)d_out, 1);
        else
            add_ln<<<MR, 64, 0, stream>>>(h1, xb, g2 + bD, be2 + bD,
                                          xb, nullptr, 0);
    }
}

// Round 3
// 566.530 us; speedup vs baseline: 3.0529x; 1.0985x over previous
//
#include <hip/hip_runtime.h>
#include <math.h>

// Problem constants
#define BATCH 2
#define SEQ   2048
#define DM    768
#define NHD   12
#define NL    2
#define DFF   3072
#define DH    64
#define HW    256            // WIN // 2
#define MR    (BATCH*SEQ)    // 4096
#define EPSF  1e-5f
#define SCALE 0.125f         // DH^-0.5
#define QKVS  2304           // fused qkv activation row stride

typedef __attribute__((ext_vector_type(8))) __bf16 bf16x8;
typedef __attribute__((ext_vector_type(4))) float  f32x4;

__device__ __forceinline__ ushort f2bu(float f) {
    union { __bf16 h; ushort u; } c;
    c.h = (__bf16)f;
    return c.u;
}
__device__ __forceinline__ float bu2f(ushort u) {
    union { uint u; float f; } c;
    c.u = ((uint)u) << 16;
    return c.f;
}

// async global->LDS, 16B per lane. LDS dest must be linear: uniform base +
// lane*16 within each wave (learn_hip m104).
__device__ __forceinline__ void gload16(const ushort* g, ushort* l) {
    __builtin_amdgcn_global_load_lds(
        (const __attribute__((address_space(1))) void*)g,
        (__attribute__((address_space(3))) void*)l, 16, 0, 0);
}

// ---------------------------------------------------------------------------
// fp32 -> bf16 cast, 4 elems/thread (n divisible by 1024)
// ---------------------------------------------------------------------------
__global__ __launch_bounds__(256) void cvt(const float* __restrict__ in,
                                           ushort* __restrict__ out, int n)
{
    int i = (blockIdx.x * 256 + threadIdx.x) * 4;
    if (i >= n) return;
    float4 v = *(const float4*)(in + i);
    ushort4 o;
    o.x = f2bu(v.x); o.y = f2bu(v.y); o.z = f2bu(v.z); o.w = f2bu(v.w);
    *(ushort4*)(out + i) = o;
}

// ---------------------------------------------------------------------------
// MFMA GEMM, m97 structure: 128x128 tile, BK=32, 256 thr = 4 waves (2x2),
// each wave computes 64x64 via 4x4 mfma_f32_16x16x32_bf16 fragments.
// Staging: global_load_lds width=16, linear LDS [128][32] (no pad -- m104).
// Fragment layouts (learn_hip m89/m91, HW-verified):
//   A-frag: A[m = lane&15][k = (lane>>4)*8 + j]
//   B-frag: W[n = lane&15][k = (lane>>4)*8 + j]
//   C/D:    col(n) = lane&15, row(m) = (lane>>4)*4 + reg
// ---------------------------------------------------------------------------
__global__ __launch_bounds__(256) void gemm128(
    const ushort* __restrict__ A, const ushort* __restrict__ W,
    const float* __restrict__ bias, ushort* __restrict__ C,
    int M, int N, int K, int relu)
{
    __shared__ ushort As[128 * 32];
    __shared__ ushort Ws[128 * 32];

    const int t  = threadIdx.x;
    const int bm = blockIdx.y * 128;
    const int bn = blockIdx.x * 128;

    const int w    = t >> 6;
    const int lane = t & 63;
    const int quad = lane >> 4;
    const int lrow = lane & 15;
    const int wm   = (w >> 1) * 64;
    const int wn   = (w & 1) * 64;

    const int srow = t >> 2;          // 0..63 (e=0), +64 for e=1
    const int scol = (t & 3) * 8;
    const ushort* ag = A + (size_t)(bm + srow) * K + scol;
    const ushort* wg = W + (size_t)(bn + srow) * K + scol;
    ushort* la0 = &As[t * 8];
    ushort* la1 = &As[2048 + t * 8];
    ushort* lw0 = &Ws[t * 8];
    ushort* lw1 = &Ws[2048 + t * 8];

    f32x4 acc[4][4] = {};

    for (int k0 = 0; k0 < K; k0 += 32) {
        gload16(ag + k0,                  la0);
        gload16(ag + (size_t)64 * K + k0, la1);
        gload16(wg + k0,                  lw0);
        gload16(wg + (size_t)64 * K + k0, lw1);
        __syncthreads();

        bf16x8 af[4], bfr[4];
#pragma unroll
        for (int i = 0; i < 4; ++i)
            af[i] = *(const bf16x8*)&As[(wm + i * 16 + lrow) * 32 + quad * 8];
#pragma unroll
        for (int j = 0; j < 4; ++j)
            bfr[j] = *(const bf16x8*)&Ws[(wn + j * 16 + lrow) * 32 + quad * 8];

#pragma unroll
        for (int i = 0; i < 4; ++i)
#pragma unroll
            for (int j = 0; j < 4; ++j)
                acc[i][j] = __builtin_amdgcn_mfma_f32_16x16x32_bf16(
                    af[i], bfr[j], acc[i][j], 0, 0, 0);
        __syncthreads();
    }

#pragma unroll
    for (int j = 0; j < 4; ++j) {
        const int col = bn + wn + j * 16 + lrow;
        const float bv = bias[col];
#pragma unroll
        for (int i = 0; i < 4; ++i) {
            const int rb = bm + wm + i * 16 + quad * 4;
#pragma unroll
            for (int r = 0; r < 4; ++r) {
                float vv = acc[i][j][r] + bv;
                if (relu) vv = fmaxf(vv, 0.f);
                C[(size_t)(rb + r) * N + col] = f2bu(vv);
            }
        }
    }
}

// ---------------------------------------------------------------------------
// MFMA GEMM, BM=64 x BN=128, BK=32, 4 waves (2x2), wave = 32x64 via 2x4
// fragments. Optional split-K: blockIdx.z = K-chunk; if gridDim.z > 1, write
// fp32 partials (no bias) to part[z*M*N + ...]; else bf16 + bias (+relu).
// Kc = chunk length, ldk = row stride of A and W (= full K).
// ---------------------------------------------------------------------------
__global__ __launch_bounds__(256) void gemm64(
    const ushort* __restrict__ A, const ushort* __restrict__ W,
    const float* __restrict__ bias, ushort* __restrict__ C,
    float* __restrict__ part, int M, int N, int Kc, int ldk, int relu)
{
    __shared__ ushort As[64 * 32];
    __shared__ ushort Ws[128 * 32];

    const int t  = threadIdx.x;
    const int bm = blockIdx.y * 64;
    const int bn = blockIdx.x * 128;
    const int z  = blockIdx.z;
    const int kbase = z * Kc;

    const int w    = t >> 6;
    const int lane = t & 63;
    const int quad = lane >> 4;
    const int lrow = lane & 15;
    const int wm   = (w >> 1) * 32;
    const int wn   = (w & 1) * 64;

    const int srow = t >> 2;          // 0..63
    const int scol = (t & 3) * 8;
    const ushort* ag = A + (size_t)(bm + srow) * ldk + kbase + scol;
    const ushort* wg = W + (size_t)(bn + srow) * ldk + kbase + scol;
    ushort* la0 = &As[t * 8];
    ushort* lw0 = &Ws[t * 8];
    ushort* lw1 = &Ws[2048 + t * 8];

    f32x4 acc[2][4] = {};

    for (int k0 = 0; k0 < Kc; k0 += 32) {
        gload16(ag + k0,                    la0);
        gload16(wg + k0,                    lw0);
        gload16(wg + (size_t)64 * ldk + k0, lw1);
        __syncthreads();

        bf16x8 af[2], bfr[4];
#pragma unroll
        for (int i = 0; i < 2; ++i)
            af[i] = *(const bf16x8*)&As[(wm + i * 16 + lrow) * 32 + quad * 8];
#pragma unroll
        for (int j = 0; j < 4; ++j)
            bfr[j] = *(const bf16x8*)&Ws[(wn + j * 16 + lrow) * 32 + quad * 8];

#pragma unroll
        for (int i = 0; i < 2; ++i)
#pragma unroll
            for (int j = 0; j < 4; ++j)
                acc[i][j] = __builtin_amdgcn_mfma_f32_16x16x32_bf16(
                    af[i], bfr[j], acc[i][j], 0, 0, 0);
        __syncthreads();
    }

    if (gridDim.z > 1) {
        float* po = part + (size_t)z * M * N;
#pragma unroll
        for (int j = 0; j < 4; ++j) {
            const int col = bn + wn + j * 16 + lrow;
#pragma unroll
            for (int i = 0; i < 2; ++i) {
                const int rb = bm + wm + i * 16 + quad * 4;
#pragma unroll
                for (int r = 0; r < 4; ++r)
                    po[(size_t)(rb + r) * N + col] = acc[i][j][r];
            }
        }
    } else {
#pragma unroll
        for (int j = 0; j < 4; ++j) {
            const int col = bn + wn + j * 16 + lrow;
            const float bv = bias[col];
#pragma unroll
            for (int i = 0; i < 2; ++i) {
                const int rb = bm + wm + i * 16 + quad * 4;
#pragma unroll
                for (int r = 0; r < 4; ++r) {
                    float vv = acc[i][j][r] + bv;
                    if (relu) vv = fmaxf(vv, 0.f);
                    C[(size_t)(rb + r) * N + col] = f2bu(vv);
                }
            }
        }
    }
}

// ---------------------------------------------------------------------------
// split-K reduce: out[i] = bf16(p[i] + p[MR*DM + i] + bias[i % DM])
// ---------------------------------------------------------------------------
__global__ __launch_bounds__(256) void red_sk(
    const float* __restrict__ p, const float* __restrict__ bias,
    ushort* __restrict__ out)
{
    const int i = (blockIdx.x * 256 + threadIdx.x) * 4;
    float4 a = *(const float4*)(p + i);
    float4 b = *(const float4*)(p + (size_t)MR * DM + i);
    const int col = i % DM;               // i%4==0, DM%4==0 -> no wrap
    float4 bv = *(const float4*)(bias + col);
    ushort4 o;
    o.x = f2bu(a.x + b.x + bv.x);
    o.y = f2bu(a.y + b.y + bv.y);
    o.z = f2bu(a.z + b.z + bv.z);
    o.w = f2bu(a.w + b.w + bv.w);
    *(ushort4*)(out + i) = o;
}

// ---------------------------------------------------------------------------
// Banded attention, MFMA version. Block = (32 queries, head, batch), 256 thr
// = 4 waves. q/k/v come from the fused QKV buffer (row stride QKVS); o is
// written at DM stride. Union key window: 9 chunks of 64 keys.
// ---------------------------------------------------------------------------
#define QT  32
#define NCH 9    // 9*64 = 576 >= 32+512
#define KP  72   // kv/qs pitch in bf16 (144 B rows: 16B-aligned, 2-way max)
#define SCP 584  // score pitch in bf16 (1168 B rows: 16B-aligned, 2-way max)

__global__ __launch_bounds__(256) void attn(
    const ushort* __restrict__ q, const ushort* __restrict__ k,
    const ushort* __restrict__ v, ushort* __restrict__ o)
{
    __shared__ ushort qs[QT][KP];
    __shared__ ushort kv[64][KP];
    __shared__ ushort sc[QT][SCP];
    __shared__ float  rinv[QT];

    const int t    = threadIdx.x;
    const int i0   = blockIdx.x * QT;
    const int h    = blockIdx.y;
    const int b    = blockIdx.z;
    const size_t ibase = (size_t)b * SEQ * QKVS + (size_t)h * DH;  // q/k/v
    const size_t obase = (size_t)b * SEQ * DM   + (size_t)h * DH;  // o

    const int w    = t >> 6;
    const int lane = t & 63;
    const int quad = lane >> 4;
    const int lrow = lane & 15;
    const int qrow = (w >> 1) * 16;     // wave's 16-query sub-tile

    // ---- stage Q: 32 rows x 64 dh, one uint4 per thread -------------------
    {
        int qi = t >> 3, d0 = (t & 7) * 8;
        uint4 raw = *(const uint4*)(q + ibase + (size_t)(i0 + qi) * QKVS + d0);
        *(uint4*)&qs[qi][d0] = raw;
    }
    __syncthreads();

    // Q fragments are chunk-invariant: hoist.
    const bf16x8 a0 = *(const bf16x8*)&qs[qrow + lrow][quad * 8];
    const bf16x8 a1 = *(const bf16x8*)&qs[qrow + lrow][32 + quad * 8];

    const int jstart = i0 - HW;

    // ---- pass 1: QK^T into sc (bf16), masked + scaled ---------------------
    for (int c = 0; c < NCH; ++c) {
        const int j0 = jstart + c * 64;
#pragma unroll
        for (int e = 0; e < 2; ++e) {
            int idx = t + 256 * e;
            int jj = idx >> 3, d0 = (idx & 7) * 8;
            int j = j0 + jj;
            uint4 raw = make_uint4(0, 0, 0, 0);
            if (j >= 0 && j < SEQ)
                raw = *(const uint4*)(k + ibase + (size_t)j * QKVS + d0);
            *(uint4*)&kv[jj][d0] = raw;
        }
        __syncthreads();

#pragma unroll
        for (int kt = 0; kt < 2; ++kt) {
            const int krow = (w & 1) * 32 + kt * 16;
            bf16x8 b0 = *(const bf16x8*)&kv[krow + lrow][quad * 8];
            bf16x8 b1 = *(const bf16x8*)&kv[krow + lrow][32 + quad * 8];
            f32x4 acc = {};
            acc = __builtin_amdgcn_mfma_f32_16x16x32_bf16(a0, b0, acc, 0, 0, 0);
            acc = __builtin_amdgcn_mfma_f32_16x16x32_bf16(a1, b1, acc, 0, 0, 0);
            const int jg = j0 + krow + lrow;
#pragma unroll
            for (int r = 0; r < 4; ++r) {
                const int qi = qrow + quad * 4 + r;
                const int ig = i0 + qi;
                bool ok = (jg >= 0) && (jg < SEQ) &&
                          (jg >= ig - HW) && (jg <= ig + HW);
                float s = ok ? acc[r] * SCALE : -1e30f;
                sc[qi][c * 64 + krow + lrow] = f2bu(s);
            }
        }
        __syncthreads();
    }

    // ---- softmax: 8 lanes per row -----------------------------------------
    {
        const int r = t >> 3, l8 = t & 7;
        float mx = -1e30f;
        for (int cix = l8; cix < NCH * 64; cix += 8)
            mx = fmaxf(mx, bu2f(sc[r][cix]));
#pragma unroll
        for (int off = 4; off; off >>= 1) mx = fmaxf(mx, __shfl_xor(mx, off));
        float sum = 0.f;
        for (int cix = l8; cix < NCH * 64; cix += 8) {
            float e = __expf(bu2f(sc[r][cix]) - mx);
            sc[r][cix] = f2bu(e);
            sum += e;
        }
#pragma unroll
        for (int off = 4; off; off >>= 1) sum += __shfl_xor(sum, off);
        if (l8 == 0) rinv[r] = 1.f / sum;
    }
    __syncthreads();

    // ---- pass 2: O = P.V ---------------------------------------------------
    f32x4 oacc[2] = {};
    const int nbase = (w & 1) * 32;     // wave's 32-wide dh sub-tile

    for (int c = 0; c < NCH; ++c) {
        const int j0 = jstart + c * 64;
#pragma unroll
        for (int e = 0; e < 2; ++e) {
            int idx = t + 256 * e;
            int jj = idx >> 3, d0 = (idx & 7) * 8;
            int j = j0 + jj;
            uint4 raw = make_uint4(0, 0, 0, 0);
            if (j >= 0 && j < SEQ)
                raw = *(const uint4*)(v + ibase + (size_t)j * QKVS + d0);
            const ushort* u = (const ushort*)&raw;
            // transposed, XOR-swizzled store: vt[dh][key]
#pragma unroll
            for (int x = 0; x < 8; ++x) {
                int dh  = d0 + x;
                int blk = ((jj >> 3) ^ (dh >> 3)) & 7;
                kv[dh][blk * 8 + (jj & 7)] = u[x];
            }
        }
        __syncthreads();

        bf16x8 pa0 = *(const bf16x8*)&sc[qrow + lrow][c * 64 + quad * 8];
        bf16x8 pa1 = *(const bf16x8*)&sc[qrow + lrow][c * 64 + 32 + quad * 8];
#pragma unroll
        for (int nt = 0; nt < 2; ++nt) {
            const int dh  = nbase + nt * 16 + lrow;
            const int rsw = (dh >> 3) & 7;
            bf16x8 b0 = *(const bf16x8*)&kv[dh][((quad)     ^ rsw) * 8];
            bf16x8 b1 = *(const bf16x8*)&kv[dh][((quad + 4) ^ rsw) * 8];
            oacc[nt] = __builtin_amdgcn_mfma_f32_16x16x32_bf16(pa0, b0, oacc[nt], 0, 0, 0);
            oacc[nt] = __builtin_amdgcn_mfma_f32_16x16x32_bf16(pa1, b1, oacc[nt], 0, 0, 0);
        }
        __syncthreads();
    }

    // ---- write O: col(dh) = lane&15, row(q) = quad*4 + r ------------------
#pragma unroll
    for (int nt = 0; nt < 2; ++nt) {
        const int dcol = nbase + nt * 16 + lrow;
#pragma unroll
        for (int r = 0; r < 4; ++r) {
            const int qi = qrow + quad * 4 + r;
            o[obase + (size_t)(i0 + qi) * DM + dcol] = f2bu(oacc[nt][r] * rinv[qi]);
        }
    }
}

// ---------------------------------------------------------------------------
// Residual + LayerNorm, one wave per row. bf16 in; bf16 out or fp32 (final).
// ---------------------------------------------------------------------------
__global__ __launch_bounds__(64) void add_ln(
    const ushort* __restrict__ xa, const ushort* __restrict__ yb,
    const float* __restrict__ g, const float* __restrict__ be,
    ushort* __restrict__ ob, float* __restrict__ of, int fin)
{
    const int r = blockIdx.x, t = threadIdx.x;
    const size_t off = (size_t)r * DM;
    float sv[12];
    float s1 = 0.f, s2 = 0.f;
#pragma unroll
    for (int ii = 0; ii < 12; ++ii) {
        float vv = bu2f(xa[off + t + 64 * ii]) + bu2f(yb[off + t + 64 * ii]);
        sv[ii] = vv; s1 += vv; s2 += vv * vv;
    }
#pragma unroll
    for (int o2 = 32; o2; o2 >>= 1) {
        s1 += __shfl_xor(s1, o2);
        s2 += __shfl_xor(s2, o2);
    }
    const float mean = s1 * (1.f / 768.f);
    const float rstd = rsqrtf(s2 * (1.f / 768.f) - mean * mean + EPSF);
#pragma unroll
    for (int ii = 0; ii < 12; ++ii) {
        const int c = t + 64 * ii;
        float v = (sv[ii] - mean) * rstd * g[c] + be[c];
        if (fin) of[off + c] = v;
        else     ob[off + c] = f2bu(v);
    }
}

// ---------------------------------------------------------------------------
// Host orchestration.
// ---------------------------------------------------------------------------
extern "C" void kernel_launch(void* const* d_in, const int* in_sizes, int n_in,
                              void* d_out, int out_size, void* d_ws, size_t ws_size,
                              hipStream_t stream) {
    (void)in_sizes; (void)n_in; (void)out_size; (void)ws_size;
    const float* src = (const float*)d_in[0];
    const float* qw  = (const float*)d_in[1];
    const float* qb  = (const float*)d_in[2];
    const float* kw  = (const float*)d_in[3];
    const float* kb  = (const float*)d_in[4];
    const float* vw  = (const float*)d_in[5];
    const float* vb  = (const float*)d_in[6];
    const float* ow  = (const float*)d_in[7];
    const float* ob  = (const float*)d_in[8];
    const float* w1  = (const float*)d_in[9];
    const float* b1  = (const float*)d_in[10];
    const float* w2  = (const float*)d_in[11];
    const float* b2  = (const float*)d_in[12];
    const float* g1  = (const float*)d_in[13];
    const float* be1 = (const float*)d_in[14];
    const float* g2  = (const float*)d_in[15];
    const float* be2 = (const float*)d_in[16];

    const size_t A    = (size_t)MR * DM;         // 3,145,728
    const size_t WD1  = (size_t)DM * DM;         // 589,824  (per layer)
    const size_t WQKV = (size_t)3 * DM * DM;     // 1,769,472 (per layer)
    const size_t WF1  = (size_t)DFF * DM;        // 2,359,296 (per layer)
    const size_t WF   = (size_t)NL * WF1;        // 4,718,592

    float*  bcat = (float*)d_ws;                 // NL * 2304 fp32
    ushort* p    = (ushort*)(bcat + (size_t)NL * QKVS);
    ushort* qkvwB = p; p += (size_t)NL * WQKV;
    ushort* owB   = p; p += (size_t)NL * WD1;
    ushort* w1B   = p; p += WF;
    ushort* w2B   = p; p += WF;
    ushort* xb    = p; p += A;
    ushort* qkvB  = p; p += 3 * A;
    ushort* oB    = p; p += A;
    ushort* yB    = p; p += A;
    ushort* h1    = p; p += A;
    ushort* ffh   = p;                            // MR*DFF = 12.58M elems

    // split-K fp32 partials: alias the dead-at-FF2 region qkvB..yB
    // (3A+A+A = 5A ushorts = 31.45 MB >= 2*MR*DM*4B = 25.17 MB)
    float* part = (float*)qkvB;

    // bias concat (device-to-device, async on stream — graph-capture safe)
    for (int l = 0; l < NL; ++l) {
        hipMemcpyAsync(bcat + (size_t)l * QKVS + 0,    qb + (size_t)l * DM,
                       DM * sizeof(float), hipMemcpyDeviceToDevice, stream);
        hipMemcpyAsync(bcat + (size_t)l * QKVS + DM,   kb + (size_t)l * DM,
                       DM * sizeof(float), hipMemcpyDeviceToDevice, stream);
        hipMemcpyAsync(bcat + (size_t)l * QKVS + 2*DM, vb + (size_t)l * DM,
                       DM * sizeof(float), hipMemcpyDeviceToDevice, stream);
    }

    // weight + src conversion (all sizes divisible by 1024)
    for (int l = 0; l < NL; ++l) {
        cvt<<<(int)(WD1 / 1024), 256, 0, stream>>>(
            qw + (size_t)l * WD1, qkvwB + (size_t)l * WQKV + 0,     (int)WD1);
        cvt<<<(int)(WD1 / 1024), 256, 0, stream>>>(
            kw + (size_t)l * WD1, qkvwB + (size_t)l * WQKV + WD1,   (int)WD1);
        cvt<<<(int)(WD1 / 1024), 256, 0, stream>>>(
            vw + (size_t)l * WD1, qkvwB + (size_t)l * WQKV + 2*WD1, (int)WD1);
    }
    cvt<<<(int)(NL * WD1 / 1024), 256, 0, stream>>>(ow, owB, (int)(NL * WD1));
    cvt<<<(int)(WF / 1024), 256, 0, stream>>>(w1, w1B, (int)WF);
    cvt<<<(int)(WF / 1024), 256, 0, stream>>>(w2, w2B, (int)WF);
    cvt<<<(int)(A  / 1024), 256, 0, stream>>>(src, xb, (int)A);

    const dim3 gQKV(QKVS / 128, MR / 128);      // (18, 32)  576 blocks
    const dim3 gO(DM / 128, MR / 64);           // (6, 64)   384 blocks
    const dim3 gF1(DFF / 128, MR / 128);        // (24, 32)  768 blocks
    const dim3 gF2(DM / 128, MR / 64, 2);       // (6, 64, 2) 768 blocks
    const dim3 gA(SEQ / QT, NHD, BATCH);        // (64, 12, 2)

    for (int l = 0; l < NL; ++l) {
        const size_t bD = (size_t)l * DM;
        const size_t bF = (size_t)l * DFF;

        gemm128<<<gQKV, 256, 0, stream>>>(xb, qkvwB + (size_t)l * WQKV,
                                          bcat + (size_t)l * QKVS, qkvB,
                                          MR, QKVS, DM, 0);
        attn<<<gA, 256, 0, stream>>>(qkvB, qkvB + DM, qkvB + 2 * DM, oB);
        gemm64<<<gO, 256, 0, stream>>>(oB, owB + (size_t)l * WD1, ob + bD, yB,
                                       nullptr, MR, DM, DM, DM, 0);
        add_ln<<<MR, 64, 0, stream>>>(xb, yB, g1 + bD, be1 + bD,
                                      h1, nullptr, 0);
        gemm128<<<gF1, 256, 0, stream>>>(h1, w1B + (size_t)l * WF1, b1 + bF, ffh,
                                         MR, DFF, DM, 1);
        // FF2 split-K: K=3072 -> 2 chunks of 1536; fp32 partials + reduce
        gemm64<<<gF2, 256, 0, stream>>>(ffh, w2B + (size_t)l * WF1, nullptr,
                                        nullptr, part, MR, DM, DFF / 2, DFF, 0);
        red_sk<<<(int)(A / 1024), 256, 0, stream>>>(part, b2 + bD, xb);
        if (l == NL - 1)
            add_ln<<<MR, 64, 0, stream>>>(h1, xb, g2 + bD, be2 + bD,
                                          nullptr, (float*)d_out, 1);
        else
            add_ln<<<MR, 64, 0, stream>>>(h1, xb, g2 + bD, be2 + bD,
                                          xb, nullptr, 0);
    }
}

// Round 4
// 513.309 us; speedup vs baseline: 3.3694x; 1.1037x over previous
//
#include <hip/hip_runtime.h>
#include <math.h>

// Problem constants
#define BATCH 2
#define SEQ   2048
#define DM    768
#define NHD   12
#define NL    2
#define DFF   3072
#define DH    64
#define HW    256            // WIN // 2
#define MR    (BATCH*SEQ)    // 4096
#define EPSF  1e-5f
#define SCALE 0.125f         // DH^-0.5
#define QKVS  2304           // fused qkv activation row stride

typedef __attribute__((ext_vector_type(8))) __bf16 bf16x8;
typedef __attribute__((ext_vector_type(4))) float  f32x4;

__device__ __forceinline__ ushort f2bu(float f) {
    union { __bf16 h; ushort u; } c;
    c.h = (__bf16)f;
    return c.u;
}
__device__ __forceinline__ float bu2f(ushort u) {
    union { uint u; float f; } c;
    c.u = ((uint)u) << 16;
    return c.f;
}

// async global->LDS, 16B per lane. LDS dest must be linear: uniform base +
// lane*16 within each wave (learn_hip m104).
__device__ __forceinline__ void gload16(const ushort* g, ushort* l) {
    __builtin_amdgcn_global_load_lds(
        (const __attribute__((address_space(1))) void*)g,
        (__attribute__((address_space(3))) void*)l, 16, 0, 0);
}

// ---------------------------------------------------------------------------
// fp32 -> bf16 cast, 4 elems/thread (n divisible by 1024)
// ---------------------------------------------------------------------------
__global__ __launch_bounds__(256) void cvt(const float* __restrict__ in,
                                           ushort* __restrict__ out, int n)
{
    int i = (blockIdx.x * 256 + threadIdx.x) * 4;
    if (i >= n) return;
    float4 v = *(const float4*)(in + i);
    ushort4 o;
    o.x = f2bu(v.x); o.y = f2bu(v.y); o.z = f2bu(v.z); o.w = f2bu(v.w);
    *(ushort4*)(out + i) = o;
}

// ---------------------------------------------------------------------------
// MFMA GEMM, m97 structure: 128x128 tile, BK=32, 256 thr = 4 waves (2x2),
// each wave computes 64x64 via 4x4 mfma_f32_16x16x32_bf16 fragments.
// Staging: global_load_lds width=16, linear LDS [128][32] (no pad -- m104).
// Fragment layouts (learn_hip m89/m91, HW-verified):
//   A-frag: A[m = lane&15][k = (lane>>4)*8 + j]
//   B-frag: W[n = lane&15][k = (lane>>4)*8 + j]
//   C/D:    col(n) = lane&15, row(m) = (lane>>4)*4 + reg
// ---------------------------------------------------------------------------
__global__ __launch_bounds__(256) void gemm128(
    const ushort* __restrict__ A, const ushort* __restrict__ W,
    const float* __restrict__ bias, ushort* __restrict__ C,
    int M, int N, int K, int relu)
{
    __shared__ ushort As[128 * 32];
    __shared__ ushort Ws[128 * 32];

    const int t  = threadIdx.x;
    const int bm = blockIdx.y * 128;
    const int bn = blockIdx.x * 128;

    const int w    = t >> 6;
    const int lane = t & 63;
    const int quad = lane >> 4;
    const int lrow = lane & 15;
    const int wm   = (w >> 1) * 64;
    const int wn   = (w & 1) * 64;

    const int srow = t >> 2;          // 0..63 (e=0), +64 for e=1
    const int scol = (t & 3) * 8;
    const ushort* ag = A + (size_t)(bm + srow) * K + scol;
    const ushort* wg = W + (size_t)(bn + srow) * K + scol;
    ushort* la0 = &As[t * 8];
    ushort* la1 = &As[2048 + t * 8];
    ushort* lw0 = &Ws[t * 8];
    ushort* lw1 = &Ws[2048 + t * 8];

    f32x4 acc[4][4] = {};

    for (int k0 = 0; k0 < K; k0 += 32) {
        gload16(ag + k0,                  la0);
        gload16(ag + (size_t)64 * K + k0, la1);
        gload16(wg + k0,                  lw0);
        gload16(wg + (size_t)64 * K + k0, lw1);
        __syncthreads();

        bf16x8 af[4], bfr[4];
#pragma unroll
        for (int i = 0; i < 4; ++i)
            af[i] = *(const bf16x8*)&As[(wm + i * 16 + lrow) * 32 + quad * 8];
#pragma unroll
        for (int j = 0; j < 4; ++j)
            bfr[j] = *(const bf16x8*)&Ws[(wn + j * 16 + lrow) * 32 + quad * 8];

#pragma unroll
        for (int i = 0; i < 4; ++i)
#pragma unroll
            for (int j = 0; j < 4; ++j)
                acc[i][j] = __builtin_amdgcn_mfma_f32_16x16x32_bf16(
                    af[i], bfr[j], acc[i][j], 0, 0, 0);
        __syncthreads();
    }

#pragma unroll
    for (int j = 0; j < 4; ++j) {
        const int col = bn + wn + j * 16 + lrow;
        const float bv = bias[col];
#pragma unroll
        for (int i = 0; i < 4; ++i) {
            const int rb = bm + wm + i * 16 + quad * 4;
#pragma unroll
            for (int r = 0; r < 4; ++r) {
                float vv = acc[i][j][r] + bv;
                if (relu) vv = fmaxf(vv, 0.f);
                C[(size_t)(rb + r) * N + col] = f2bu(vv);
            }
        }
    }
}

// ---------------------------------------------------------------------------
// MFMA GEMM, BM=64 x BN=128, BK=32, 4 waves (2x2), wave = 32x64 via 2x4
// fragments. Optional split-K: blockIdx.z = K-chunk; if gridDim.z > 1, write
// fp32 partials (no bias) to part[z*M*N + ...]; else bf16 + bias (+relu).
// Kc = chunk length, ldk = row stride of A and W (= full K).
// ---------------------------------------------------------------------------
__global__ __launch_bounds__(256) void gemm64(
    const ushort* __restrict__ A, const ushort* __restrict__ W,
    const float* __restrict__ bias, ushort* __restrict__ C,
    float* __restrict__ part, int M, int N, int Kc, int ldk, int relu)
{
    __shared__ ushort As[64 * 32];
    __shared__ ushort Ws[128 * 32];

    const int t  = threadIdx.x;
    const int bm = blockIdx.y * 64;
    const int bn = blockIdx.x * 128;
    const int z  = blockIdx.z;
    const int kbase = z * Kc;

    const int w    = t >> 6;
    const int lane = t & 63;
    const int quad = lane >> 4;
    const int lrow = lane & 15;
    const int wm   = (w >> 1) * 32;
    const int wn   = (w & 1) * 64;

    const int srow = t >> 2;          // 0..63
    const int scol = (t & 3) * 8;
    const ushort* ag = A + (size_t)(bm + srow) * ldk + kbase + scol;
    const ushort* wg = W + (size_t)(bn + srow) * ldk + kbase + scol;
    ushort* la0 = &As[t * 8];
    ushort* lw0 = &Ws[t * 8];
    ushort* lw1 = &Ws[2048 + t * 8];

    f32x4 acc[2][4] = {};

    for (int k0 = 0; k0 < Kc; k0 += 32) {
        gload16(ag + k0,                    la0);
        gload16(wg + k0,                    lw0);
        gload16(wg + (size_t)64 * ldk + k0, lw1);
        __syncthreads();

        bf16x8 af[2], bfr[4];
#pragma unroll
        for (int i = 0; i < 2; ++i)
            af[i] = *(const bf16x8*)&As[(wm + i * 16 + lrow) * 32 + quad * 8];
#pragma unroll
        for (int j = 0; j < 4; ++j)
            bfr[j] = *(const bf16x8*)&Ws[(wn + j * 16 + lrow) * 32 + quad * 8];

#pragma unroll
        for (int i = 0; i < 2; ++i)
#pragma unroll
            for (int j = 0; j < 4; ++j)
                acc[i][j] = __builtin_amdgcn_mfma_f32_16x16x32_bf16(
                    af[i], bfr[j], acc[i][j], 0, 0, 0);
        __syncthreads();
    }

    if (gridDim.z > 1) {
        float* po = part + (size_t)z * M * N;
#pragma unroll
        for (int j = 0; j < 4; ++j) {
            const int col = bn + wn + j * 16 + lrow;
#pragma unroll
            for (int i = 0; i < 2; ++i) {
                const int rb = bm + wm + i * 16 + quad * 4;
#pragma unroll
                for (int r = 0; r < 4; ++r)
                    po[(size_t)(rb + r) * N + col] = acc[i][j][r];
            }
        }
    } else {
#pragma unroll
        for (int j = 0; j < 4; ++j) {
            const int col = bn + wn + j * 16 + lrow;
            const float bv = bias[col];
#pragma unroll
            for (int i = 0; i < 2; ++i) {
                const int rb = bm + wm + i * 16 + quad * 4;
#pragma unroll
                for (int r = 0; r < 4; ++r) {
                    float vv = acc[i][j][r] + bv;
                    if (relu) vv = fmaxf(vv, 0.f);
                    C[(size_t)(rb + r) * N + col] = f2bu(vv);
                }
            }
        }
    }
}

// ---------------------------------------------------------------------------
// split-K reduce: out[i] = bf16(p[i] + p[MR*DM + i] + bias[i % DM])
// ---------------------------------------------------------------------------
__global__ __launch_bounds__(256) void red_sk(
    const float* __restrict__ p, const float* __restrict__ bias,
    ushort* __restrict__ out)
{
    const int i = (blockIdx.x * 256 + threadIdx.x) * 4;
    float4 a = *(const float4*)(p + i);
    float4 b = *(const float4*)(p + (size_t)MR * DM + i);
    const int col = i % DM;               // i%4==0, DM%4==0 -> no wrap
    float4 bv = *(const float4*)(bias + col);
    ushort4 o;
    o.x = f2bu(a.x + b.x + bv.x);
    o.y = f2bu(a.y + b.y + bv.y);
    o.z = f2bu(a.z + b.z + bv.z);
    o.w = f2bu(a.w + b.w + bv.w);
    *(ushort4*)(out + i) = o;
}

// ---------------------------------------------------------------------------
// Banded attention, fused flash-style single pass. Block = (64 queries, head,
// batch), 256 thr = 4 waves; wave w owns query rows [w*16, w*16+16) end to
// end. Per 64-key chunk: stage K[key][dh] + V^T[dh][key] (XOR-swizzled) ->
// QK^T (4 kt tiles) -> online softmax in registers (shfl over the 16-lane
// lrow group; m init -1e20, mask -1e30 so fully-masked chunks contribute 0)
// -> P tile to sc (own rows; no cross-wave hazard) -> PV. 2 barriers/chunk.
// LDS 27.6 KB (was 51.7), phases 9 (was 18).
// ---------------------------------------------------------------------------
#define QT  64
#define NCH 9    // union window 64+512 = 576 keys
#define KP  72   // LDS pitch in bf16 (144 B rows: 16B-aligned, 2-way max)

__global__ __launch_bounds__(256) void attn(
    const ushort* __restrict__ q, const ushort* __restrict__ k,
    const ushort* __restrict__ v, ushort* __restrict__ o)
{
    __shared__ ushort kv[64][KP];   // K chunk [key][dh]
    __shared__ ushort vt[64][KP];   // V^T chunk [dh][key], XOR-swizzled
    __shared__ ushort sc[QT][KP];   // Q staging, then per-chunk P tiles

    const int t    = threadIdx.x;
    const int i0   = blockIdx.x * QT;
    const int h    = blockIdx.y;
    const int b    = blockIdx.z;
    const size_t ibase = (size_t)b * SEQ * QKVS + (size_t)h * DH;  // q/k/v
    const size_t obase = (size_t)b * SEQ * DM   + (size_t)h * DH;  // o

    const int w    = t >> 6;
    const int lane = t & 63;
    const int quad = lane >> 4;
    const int lrow = lane & 15;
    const int qrow = w * 16;            // wave's 16 query rows

    // ---- stage Q into sc: 64 rows x 64 dh, 2 uint4/thread -----------------
#pragma unroll
    for (int e = 0; e < 2; ++e) {
        int idx = t + 256 * e;
        int qi = idx >> 3, d0 = (idx & 7) * 8;
        uint4 raw = *(const uint4*)(q + ibase + (size_t)(i0 + qi) * QKVS + d0);
        *(uint4*)&sc[qi][d0] = raw;
    }
    __syncthreads();

    // Q fragments (chunk-invariant); after this each wave touches only its
    // own sc rows, so sc is safely reused for P tiles.
    const bf16x8 a0 = *(const bf16x8*)&sc[qrow + lrow][quad * 8];
    const bf16x8 a1 = *(const bf16x8*)&sc[qrow + lrow][32 + quad * 8];

    float m_r[4], l_r[4];
    f32x4 oacc[4] = {};
#pragma unroll
    for (int r = 0; r < 4; ++r) { m_r[r] = -1e20f; l_r[r] = 0.f; }

    const int jstart = i0 - HW;

    for (int c = 0; c < NCH; ++c) {
        const int j0 = jstart + c * 64;

        // ---- stage K [key][dh] + V^T [dh][key] (XOR-swizzled scatter) -----
#pragma unroll
        for (int e = 0; e < 2; ++e) {
            int idx = t + 256 * e;
            int jj = idx >> 3, d0 = (idx & 7) * 8;
            int j = j0 + jj;
            uint4 kr = make_uint4(0, 0, 0, 0);
            uint4 vr = make_uint4(0, 0, 0, 0);
            if (j >= 0 && j < SEQ) {
                kr = *(const uint4*)(k + ibase + (size_t)j * QKVS + d0);
                vr = *(const uint4*)(v + ibase + (size_t)j * QKVS + d0);
            }
            *(uint4*)&kv[jj][d0] = kr;
            const ushort* u = (const ushort*)&vr;
#pragma unroll
            for (int x = 0; x < 8; ++x) {
                int dh  = d0 + x;
                int blk = ((jj >> 3) ^ (dh >> 3)) & 7;
                vt[dh][blk * 8 + (jj & 7)] = u[x];
            }
        }
        __syncthreads();

        // ---- QK^T: 4 kt tiles of 16 keys, masked + scaled -----------------
        float p[4][4];   // [kt][r]
#pragma unroll
        for (int kt = 0; kt < 4; ++kt) {
            const int krow = kt * 16;
            bf16x8 b0 = *(const bf16x8*)&kv[krow + lrow][quad * 8];
            bf16x8 b1 = *(const bf16x8*)&kv[krow + lrow][32 + quad * 8];
            f32x4 acc = {};
            acc = __builtin_amdgcn_mfma_f32_16x16x32_bf16(a0, b0, acc, 0, 0, 0);
            acc = __builtin_amdgcn_mfma_f32_16x16x32_bf16(a1, b1, acc, 0, 0, 0);
            const int jg = j0 + krow + lrow;
#pragma unroll
            for (int r = 0; r < 4; ++r) {
                const int ig = i0 + qrow + quad * 4 + r;
                bool ok = (jg >= 0) && (jg < SEQ) &&
                          (jg >= ig - HW) && (jg <= ig + HW);
                p[kt][r] = ok ? acc[r] * SCALE : -1e30f;
            }
        }

        // ---- online softmax (per query row; reduce over 16-lane group) ----
#pragma unroll
        for (int r = 0; r < 4; ++r) {
            float cm = fmaxf(fmaxf(p[0][r], p[1][r]), fmaxf(p[2][r], p[3][r]));
#pragma unroll
            for (int off = 8; off; off >>= 1) cm = fmaxf(cm, __shfl_xor(cm, off));
            const float mn = fmaxf(m_r[r], cm);
            const float f  = __expf(m_r[r] - mn);
            m_r[r] = mn;
            float cs = 0.f;
#pragma unroll
            for (int kt = 0; kt < 4; ++kt) {
                float e = __expf(p[kt][r] - mn);
                p[kt][r] = e;
                cs += e;
            }
#pragma unroll
            for (int off = 8; off; off >>= 1) cs += __shfl_xor(cs, off);
            l_r[r] = l_r[r] * f + cs;
#pragma unroll
            for (int nt = 0; nt < 4; ++nt) oacc[nt][r] *= f;
        }

        // ---- P tile to sc (own wave's rows only) --------------------------
#pragma unroll
        for (int kt = 0; kt < 4; ++kt)
#pragma unroll
            for (int r = 0; r < 4; ++r)
                sc[qrow + quad * 4 + r][kt * 16 + lrow] = f2bu(p[kt][r]);

        // ---- PV: O[q][dh] += P . V^T --------------------------------------
        bf16x8 pa0 = *(const bf16x8*)&sc[qrow + lrow][quad * 8];
        bf16x8 pa1 = *(const bf16x8*)&sc[qrow + lrow][32 + quad * 8];
#pragma unroll
        for (int nt = 0; nt < 4; ++nt) {
            const int dh  = nt * 16 + lrow;
            const int rsw = (dh >> 3) & 7;
            bf16x8 b0 = *(const bf16x8*)&vt[dh][((quad)     ^ rsw) * 8];
            bf16x8 b1 = *(const bf16x8*)&vt[dh][((quad + 4) ^ rsw) * 8];
            oacc[nt] = __builtin_amdgcn_mfma_f32_16x16x32_bf16(pa0, b0, oacc[nt], 0, 0, 0);
            oacc[nt] = __builtin_amdgcn_mfma_f32_16x16x32_bf16(pa1, b1, oacc[nt], 0, 0, 0);
        }
        __syncthreads();   // protect kv/vt restage next chunk
    }

    // ---- write O: col(dh) = nt*16 + lrow, row(q) = qrow + quad*4 + r ------
#pragma unroll
    for (int r = 0; r < 4; ++r) {
        const float inv = 1.f / l_r[r];
        const int qi = i0 + qrow + quad * 4 + r;
#pragma unroll
        for (int nt = 0; nt < 4; ++nt)
            o[obase + (size_t)qi * DM + nt * 16 + lrow] = f2bu(oacc[nt][r] * inv);
    }
}

// ---------------------------------------------------------------------------
// Residual + LayerNorm, one wave per row. bf16 in; bf16 out or fp32 (final).
// ---------------------------------------------------------------------------
__global__ __launch_bounds__(64) void add_ln(
    const ushort* __restrict__ xa, const ushort* __restrict__ yb,
    const float* __restrict__ g, const float* __restrict__ be,
    ushort* __restrict__ ob, float* __restrict__ of, int fin)
{
    const int r = blockIdx.x, t = threadIdx.x;
    const size_t off = (size_t)r * DM;
    float sv[12];
    float s1 = 0.f, s2 = 0.f;
#pragma unroll
    for (int ii = 0; ii < 12; ++ii) {
        float vv = bu2f(xa[off + t + 64 * ii]) + bu2f(yb[off + t + 64 * ii]);
        sv[ii] = vv; s1 += vv; s2 += vv * vv;
    }
#pragma unroll
    for (int o2 = 32; o2; o2 >>= 1) {
        s1 += __shfl_xor(s1, o2);
        s2 += __shfl_xor(s2, o2);
    }
    const float mean = s1 * (1.f / 768.f);
    const float rstd = rsqrtf(s2 * (1.f / 768.f) - mean * mean + EPSF);
#pragma unroll
    for (int ii = 0; ii < 12; ++ii) {
        const int c = t + 64 * ii;
        float v = (sv[ii] - mean) * rstd * g[c] + be[c];
        if (fin) of[off + c] = v;
        else     ob[off + c] = f2bu(v);
    }
}

// ---------------------------------------------------------------------------
// Host orchestration.
// ---------------------------------------------------------------------------
extern "C" void kernel_launch(void* const* d_in, const int* in_sizes, int n_in,
                              void* d_out, int out_size, void* d_ws, size_t ws_size,
                              hipStream_t stream) {
    (void)in_sizes; (void)n_in; (void)out_size; (void)ws_size;
    const float* src = (const float*)d_in[0];
    const float* qw  = (const float*)d_in[1];
    const float* qb  = (const float*)d_in[2];
    const float* kw  = (const float*)d_in[3];
    const float* kb  = (const float*)d_in[4];
    const float* vw  = (const float*)d_in[5];
    const float* vb  = (const float*)d_in[6];
    const float* ow  = (const float*)d_in[7];
    const float* ob  = (const float*)d_in[8];
    const float* w1  = (const float*)d_in[9];
    const float* b1  = (const float*)d_in[10];
    const float* w2  = (const float*)d_in[11];
    const float* b2  = (const float*)d_in[12];
    const float* g1  = (const float*)d_in[13];
    const float* be1 = (const float*)d_in[14];
    const float* g2  = (const float*)d_in[15];
    const float* be2 = (const float*)d_in[16];

    const size_t A    = (size_t)MR * DM;         // 3,145,728
    const size_t WD1  = (size_t)DM * DM;         // 589,824  (per layer)
    const size_t WQKV = (size_t)3 * DM * DM;     // 1,769,472 (per layer)
    const size_t WF1  = (size_t)DFF * DM;        // 2,359,296 (per layer)
    const size_t WF   = (size_t)NL * WF1;        // 4,718,592

    float*  bcat = (float*)d_ws;                 // NL * 2304 fp32
    ushort* p    = (ushort*)(bcat + (size_t)NL * QKVS);
    ushort* qkvwB = p; p += (size_t)NL * WQKV;
    ushort* owB   = p; p += (size_t)NL * WD1;
    ushort* w1B   = p; p += WF;
    ushort* w2B   = p; p += WF;
    ushort* xb    = p; p += A;
    ushort* qkvB  = p; p += 3 * A;
    ushort* oB    = p; p += A;
    ushort* yB    = p; p += A;
    ushort* h1    = p; p += A;
    ushort* ffh   = p;                            // MR*DFF = 12.58M elems

    // split-K fp32 partials: alias the dead-at-FF2 region qkvB..yB
    // (3A+A+A = 5A ushorts = 31.45 MB >= 2*MR*DM*4B = 25.17 MB)
    float* part = (float*)qkvB;

    // bias concat (device-to-device, async on stream — graph-capture safe)
    for (int l = 0; l < NL; ++l) {
        hipMemcpyAsync(bcat + (size_t)l * QKVS + 0,    qb + (size_t)l * DM,
                       DM * sizeof(float), hipMemcpyDeviceToDevice, stream);
        hipMemcpyAsync(bcat + (size_t)l * QKVS + DM,   kb + (size_t)l * DM,
                       DM * sizeof(float), hipMemcpyDeviceToDevice, stream);
        hipMemcpyAsync(bcat + (size_t)l * QKVS + 2*DM, vb + (size_t)l * DM,
                       DM * sizeof(float), hipMemcpyDeviceToDevice, stream);
    }

    // weight + src conversion (all sizes divisible by 1024)
    for (int l = 0; l < NL; ++l) {
        cvt<<<(int)(WD1 / 1024), 256, 0, stream>>>(
            qw + (size_t)l * WD1, qkvwB + (size_t)l * WQKV + 0,     (int)WD1);
        cvt<<<(int)(WD1 / 1024), 256, 0, stream>>>(
            kw + (size_t)l * WD1, qkvwB + (size_t)l * WQKV + WD1,   (int)WD1);
        cvt<<<(int)(WD1 / 1024), 256, 0, stream>>>(
            vw + (size_t)l * WD1, qkvwB + (size_t)l * WQKV + 2*WD1, (int)WD1);
    }
    cvt<<<(int)(NL * WD1 / 1024), 256, 0, stream>>>(ow, owB, (int)(NL * WD1));
    cvt<<<(int)(WF / 1024), 256, 0, stream>>>(w1, w1B, (int)WF);
    cvt<<<(int)(WF / 1024), 256, 0, stream>>>(w2, w2B, (int)WF);
    cvt<<<(int)(A  / 1024), 256, 0, stream>>>(src, xb, (int)A);

    const dim3 gQKV(QKVS / 128, MR / 128);      // (18, 32)  576 blocks
    const dim3 gO(DM / 128, MR / 64);           // (6, 64)   384 blocks
    const dim3 gF1(DFF / 128, MR / 128);        // (24, 32)  768 blocks
    const dim3 gF2(DM / 128, MR / 64, 2);       // (6, 64, 2) 768 blocks
    const dim3 gA(SEQ / QT, NHD, BATCH);        // (32, 12, 2) 768 blocks

    for (int l = 0; l < NL; ++l) {
        const size_t bD = (size_t)l * DM;
        const size_t bF = (size_t)l * DFF;

        gemm128<<<gQKV, 256, 0, stream>>>(xb, qkvwB + (size_t)l * WQKV,
                                          bcat + (size_t)l * QKVS, qkvB,
                                          MR, QKVS, DM, 0);
        attn<<<gA, 256, 0, stream>>>(qkvB, qkvB + DM, qkvB + 2 * DM, oB);
        gemm64<<<gO, 256, 0, stream>>>(oB, owB + (size_t)l * WD1, ob + bD, yB,
                                       nullptr, MR, DM, DM, DM, 0);
        add_ln<<<MR, 64, 0, stream>>>(xb, yB, g1 + bD, be1 + bD,
                                      h1, nullptr, 0);
        gemm128<<<gF1, 256, 0, stream>>>(h1, w1B + (size_t)l * WF1, b1 + bF, ffh,
                                         MR, DFF, DM, 1);
        // FF2 split-K: K=3072 -> 2 chunks of 1536; fp32 partials + reduce
        gemm64<<<gF2, 256, 0, stream>>>(ffh, w2B + (size_t)l * WF1, nullptr,
                                        nullptr, part, MR, DM, DFF / 2, DFF, 0);
        red_sk<<<(int)(A / 1024), 256, 0, stream>>>(part, b2 + bD, xb);
        if (l == NL - 1)
            add_ln<<<MR, 64, 0, stream>>>(h1, xb, g2 + bD, be2 + bD,
                                          nullptr, (float*)d_out, 1);
        else
            add_ln<<<MR, 64, 0, stream>>>(h1, xb, g2 + bD, be2 + bD,
                                          xb, nullptr, 0);
    }
}

// Round 5
// 498.303 us; speedup vs baseline: 3.4709x; 1.0301x over previous
//
#include <hip/hip_runtime.h>
#include <math.h>

// Problem constants
#define BATCH 2
#define SEQ   2048
#define DM    768
#define NHD   12
#define NL    2
#define DFF   3072
#define DH    64
#define HW    256            // WIN // 2
#define MR    (BATCH*SEQ)    // 4096
#define EPSF  1e-5f
#define SCALE 0.125f         // DH^-0.5
#define QKVS  2304           // fused qkv activation row stride

typedef __attribute__((ext_vector_type(8))) __bf16 bf16x8;
typedef __attribute__((ext_vector_type(4))) float  f32x4;

__device__ __forceinline__ ushort f2bu(float f) {
    union { __bf16 h; ushort u; } c;
    c.h = (__bf16)f;
    return c.u;
}
__device__ __forceinline__ float bu2f(ushort u) {
    union { uint u; float f; } c;
    c.u = ((uint)u) << 16;
    return c.f;
}

// async global->LDS, 16B per lane. LDS dest must be linear: uniform base +
// lane*16 within each wave (learn_hip m104).
__device__ __forceinline__ void gload16(const ushort* g, ushort* l) {
    __builtin_amdgcn_global_load_lds(
        (const __attribute__((address_space(1))) void*)g,
        (__attribute__((address_space(3))) void*)l, 16, 0, 0);
}

// XCD-aware chunked block remap (T1, m157/m192): consecutive logical tiles
// (which share operand panels) land on the SAME XCD's L2. Requires
// nwg % 8 == 0 (all swizzled grids here: 576/384/768). Pure permutation.
__device__ __forceinline__ void xcd_swz(int& bx, int& by, int& bz) {
    const int gx = gridDim.x, gy = gridDim.y;
    const int nwg = gx * gy * gridDim.z;
    int lin = bx + gx * (by + gy * bz);
    lin = (lin & 7) * (nwg >> 3) + (lin >> 3);
    bx = lin % gx;
    int rest = lin / gx;
    by = rest % gy;
    bz = rest / gy;
}

// ---------------------------------------------------------------------------
// fp32 -> bf16 cast, 4 elems/thread (n divisible by 1024)
// ---------------------------------------------------------------------------
__global__ __launch_bounds__(256) void cvt(const float* __restrict__ in,
                                           ushort* __restrict__ out, int n)
{
    int i = (blockIdx.x * 256 + threadIdx.x) * 4;
    if (i >= n) return;
    float4 v = *(const float4*)(in + i);
    ushort4 o;
    o.x = f2bu(v.x); o.y = f2bu(v.y); o.z = f2bu(v.z); o.w = f2bu(v.w);
    *(ushort4*)(out + i) = o;
}

// ---------------------------------------------------------------------------
// MFMA GEMM, m97 structure: 128x128 tile, BK=32, 256 thr = 4 waves (2x2),
// each wave computes 64x64 via 4x4 mfma_f32_16x16x32_bf16 fragments.
// Staging: global_load_lds width=16, linear LDS [128][32] (no pad -- m104).
// Fragment layouts (learn_hip m89/m91, HW-verified):
//   A-frag: A[m = lane&15][k = (lane>>4)*8 + j]
//   B-frag: W[n = lane&15][k = (lane>>4)*8 + j]
//   C/D:    col(n) = lane&15, row(m) = (lane>>4)*4 + reg
// ---------------------------------------------------------------------------
__global__ __launch_bounds__(256) void gemm128(
    const ushort* __restrict__ A, const ushort* __restrict__ W,
    const float* __restrict__ bias, ushort* __restrict__ C,
    int M, int N, int K, int relu)
{
    __shared__ ushort As[128 * 32];
    __shared__ ushort Ws[128 * 32];

    int bxi = blockIdx.x, byi = blockIdx.y, bzi = blockIdx.z;
    xcd_swz(bxi, byi, bzi);

    const int t  = threadIdx.x;
    const int bm = byi * 128;
    const int bn = bxi * 128;

    const int w    = t >> 6;
    const int lane = t & 63;
    const int quad = lane >> 4;
    const int lrow = lane & 15;
    const int wm   = (w >> 1) * 64;
    const int wn   = (w & 1) * 64;

    const int srow = t >> 2;          // 0..63 (e=0), +64 for e=1
    const int scol = (t & 3) * 8;
    const ushort* ag = A + (size_t)(bm + srow) * K + scol;
    const ushort* wg = W + (size_t)(bn + srow) * K + scol;
    ushort* la0 = &As[t * 8];
    ushort* la1 = &As[2048 + t * 8];
    ushort* lw0 = &Ws[t * 8];
    ushort* lw1 = &Ws[2048 + t * 8];

    f32x4 acc[4][4] = {};

    for (int k0 = 0; k0 < K; k0 += 32) {
        gload16(ag + k0,                  la0);
        gload16(ag + (size_t)64 * K + k0, la1);
        gload16(wg + k0,                  lw0);
        gload16(wg + (size_t)64 * K + k0, lw1);
        __syncthreads();

        bf16x8 af[4], bfr[4];
#pragma unroll
        for (int i = 0; i < 4; ++i)
            af[i] = *(const bf16x8*)&As[(wm + i * 16 + lrow) * 32 + quad * 8];
#pragma unroll
        for (int j = 0; j < 4; ++j)
            bfr[j] = *(const bf16x8*)&Ws[(wn + j * 16 + lrow) * 32 + quad * 8];

#pragma unroll
        for (int i = 0; i < 4; ++i)
#pragma unroll
            for (int j = 0; j < 4; ++j)
                acc[i][j] = __builtin_amdgcn_mfma_f32_16x16x32_bf16(
                    af[i], bfr[j], acc[i][j], 0, 0, 0);
        __syncthreads();
    }

#pragma unroll
    for (int j = 0; j < 4; ++j) {
        const int col = bn + wn + j * 16 + lrow;
        const float bv = bias[col];
#pragma unroll
        for (int i = 0; i < 4; ++i) {
            const int rb = bm + wm + i * 16 + quad * 4;
#pragma unroll
            for (int r = 0; r < 4; ++r) {
                float vv = acc[i][j][r] + bv;
                if (relu) vv = fmaxf(vv, 0.f);
                C[(size_t)(rb + r) * N + col] = f2bu(vv);
            }
        }
    }
}

// ---------------------------------------------------------------------------
// MFMA GEMM, BM=64 x BN=128, BK=32, 4 waves (2x2), wave = 32x64 via 2x4
// fragments. Optional split-K: z = K-chunk; if gridDim.z > 1, write fp32
// partials (no bias) to part[z*M*N + ...]; else bf16 + bias (+relu).
// Kc = chunk length, ldk = row stride of A and W (= full K).
// ---------------------------------------------------------------------------
__global__ __launch_bounds__(256) void gemm64(
    const ushort* __restrict__ A, const ushort* __restrict__ W,
    const float* __restrict__ bias, ushort* __restrict__ C,
    float* __restrict__ part, int M, int N, int Kc, int ldk, int relu)
{
    __shared__ ushort As[64 * 32];
    __shared__ ushort Ws[128 * 32];

    int bxi = blockIdx.x, byi = blockIdx.y, bzi = blockIdx.z;
    xcd_swz(bxi, byi, bzi);

    const int t  = threadIdx.x;
    const int bm = byi * 64;
    const int bn = bxi * 128;
    const int z  = bzi;
    const int kbase = z * Kc;

    const int w    = t >> 6;
    const int lane = t & 63;
    const int quad = lane >> 4;
    const int lrow = lane & 15;
    const int wm   = (w >> 1) * 32;
    const int wn   = (w & 1) * 64;

    const int srow = t >> 2;          // 0..63
    const int scol = (t & 3) * 8;
    const ushort* ag = A + (size_t)(bm + srow) * ldk + kbase + scol;
    const ushort* wg = W + (size_t)(bn + srow) * ldk + kbase + scol;
    ushort* la0 = &As[t * 8];
    ushort* lw0 = &Ws[t * 8];
    ushort* lw1 = &Ws[2048 + t * 8];

    f32x4 acc[2][4] = {};

    for (int k0 = 0; k0 < Kc; k0 += 32) {
        gload16(ag + k0,                    la0);
        gload16(wg + k0,                    lw0);
        gload16(wg + (size_t)64 * ldk + k0, lw1);
        __syncthreads();

        bf16x8 af[2], bfr[4];
#pragma unroll
        for (int i = 0; i < 2; ++i)
            af[i] = *(const bf16x8*)&As[(wm + i * 16 + lrow) * 32 + quad * 8];
#pragma unroll
        for (int j = 0; j < 4; ++j)
            bfr[j] = *(const bf16x8*)&Ws[(wn + j * 16 + lrow) * 32 + quad * 8];

#pragma unroll
        for (int i = 0; i < 2; ++i)
#pragma unroll
            for (int j = 0; j < 4; ++j)
                acc[i][j] = __builtin_amdgcn_mfma_f32_16x16x32_bf16(
                    af[i], bfr[j], acc[i][j], 0, 0, 0);
        __syncthreads();
    }

    if (gridDim.z > 1) {
        float* po = part + (size_t)z * M * N;
#pragma unroll
        for (int j = 0; j < 4; ++j) {
            const int col = bn + wn + j * 16 + lrow;
#pragma unroll
            for (int i = 0; i < 2; ++i) {
                const int rb = bm + wm + i * 16 + quad * 4;
#pragma unroll
                for (int r = 0; r < 4; ++r)
                    po[(size_t)(rb + r) * N + col] = acc[i][j][r];
            }
        }
    } else {
#pragma unroll
        for (int j = 0; j < 4; ++j) {
            const int col = bn + wn + j * 16 + lrow;
            const float bv = bias[col];
#pragma unroll
            for (int i = 0; i < 2; ++i) {
                const int rb = bm + wm + i * 16 + quad * 4;
#pragma unroll
                for (int r = 0; r < 4; ++r) {
                    float vv = acc[i][j][r] + bv;
                    if (relu) vv = fmaxf(vv, 0.f);
                    C[(size_t)(rb + r) * N + col] = f2bu(vv);
                }
            }
        }
    }
}

// ---------------------------------------------------------------------------
// split-K reduce: out[i] = bf16(p[i] + p[MR*DM + i] + bias[i % DM])
// ---------------------------------------------------------------------------
__global__ __launch_bounds__(256) void red_sk(
    const float* __restrict__ p, const float* __restrict__ bias,
    ushort* __restrict__ out)
{
    const int i = (blockIdx.x * 256 + threadIdx.x) * 4;
    float4 a = *(const float4*)(p + i);
    float4 b = *(const float4*)(p + (size_t)MR * DM + i);
    const int col = i % DM;               // i%4==0, DM%4==0 -> no wrap
    float4 bv = *(const float4*)(bias + col);
    ushort4 o;
    o.x = f2bu(a.x + b.x + bv.x);
    o.y = f2bu(a.y + b.y + bv.y);
    o.z = f2bu(a.z + b.z + bv.z);
    o.w = f2bu(a.w + b.w + bv.w);
    *(ushort4*)(out + i) = o;
}

// ---------------------------------------------------------------------------
// Banded attention, fused flash-style single pass, DOUBLE-BUFFERED (T14):
// Block = (64 queries, head, batch), 256 thr = 4 waves; wave w owns query
// rows [w*16, w*16+16). Per 64-key chunk: issue chunk c+1's global loads
// FIRST (latency hides under compute), compute chunk c from buf[c&1]
// (QK^T -> online softmax in regs -> P tile -> PV), then write chunk c+1's
// regs to buf[(c+1)&1], ONE barrier per chunk:
//   WAR (write buf[nxt] vs iter c-1 reads of same buf): reads end before the
//       iter-(c-1) barrier; writes start after it.
//   RAW (iter c+1 reads buf[nxt] vs iter c writes): writes end before the
//       iter-c barrier; reads start after it.
// LDS 46 KB (3 blocks/CU), 9 barriers (was 18).
// ---------------------------------------------------------------------------
#define QT  64
#define NCH 9    // union window 64+512 = 576 keys
#define KP  72   // LDS pitch in bf16 (144 B rows: 16B-aligned, 2-way max)

__global__ __launch_bounds__(256) void attn(
    const ushort* __restrict__ q, const ushort* __restrict__ k,
    const ushort* __restrict__ v, ushort* __restrict__ o)
{
    __shared__ ushort kv[2][64][KP];   // K chunk [key][dh]
    __shared__ ushort vt[2][64][KP];   // V^T chunk [dh][key], XOR-swizzled
    __shared__ ushort sc[QT][KP];      // Q staging, then per-chunk P tiles

    int bxi = blockIdx.x, byi = blockIdx.y, bzi = blockIdx.z;
    xcd_swz(bxi, byi, bzi);            // seq-neighbors share KV -> same XCD

    const int t    = threadIdx.x;
    const int i0   = bxi * QT;
    const int h    = byi;
    const int b    = bzi;
    const size_t ibase = (size_t)b * SEQ * QKVS + (size_t)h * DH;  // q/k/v
    const size_t obase = (size_t)b * SEQ * DM   + (size_t)h * DH;  // o

    const int w    = t >> 6;
    const int lane = t & 63;
    const int quad = lane >> 4;
    const int lrow = lane & 15;
    const int qrow = w * 16;            // wave's 16 query rows

    const int jstart = i0 - HW;

    // per-thread staging coords (constant across chunks)
    const int sjj[2] = { t >> 3, (t + 256) >> 3 };
    const int sd0[2] = { (t & 7) * 8, (t & 7) * 8 };

    // ---- stage Q into sc + load chunk 0 into regs -------------------------
#pragma unroll
    for (int e = 0; e < 2; ++e) {
        int idx = t + 256 * e;
        int qi = idx >> 3, d0 = (idx & 7) * 8;
        uint4 raw = *(const uint4*)(q + ibase + (size_t)(i0 + qi) * QKVS + d0);
        *(uint4*)&sc[qi][d0] = raw;
    }
    uint4 kr[2], vr[2];
#pragma unroll
    for (int e = 0; e < 2; ++e) {
        int j = jstart + sjj[e];
        kr[e] = make_uint4(0, 0, 0, 0);
        vr[e] = make_uint4(0, 0, 0, 0);
        if (j >= 0 && j < SEQ) {
            kr[e] = *(const uint4*)(k + ibase + (size_t)j * QKVS + sd0[e]);
            vr[e] = *(const uint4*)(v + ibase + (size_t)j * QKVS + sd0[e]);
        }
    }
    // write chunk 0 to buf 0 (no conflict with sc)
#pragma unroll
    for (int e = 0; e < 2; ++e) {
        *(uint4*)&kv[0][sjj[e]][sd0[e]] = kr[e];
        const ushort* u = (const ushort*)&vr[e];
#pragma unroll
        for (int x = 0; x < 8; ++x) {
            int dh  = sd0[e] + x;
            int blk = ((sjj[e] >> 3) ^ (dh >> 3)) & 7;
            vt[0][dh][blk * 8 + (sjj[e] & 7)] = u[x];
        }
    }
    __syncthreads();   // publish sc (Q) and buf0

    // Q fragments (chunk-invariant); after this each wave touches only its
    // own sc rows, so sc is safely reused for P tiles.
    const bf16x8 a0 = *(const bf16x8*)&sc[qrow + lrow][quad * 8];
    const bf16x8 a1 = *(const bf16x8*)&sc[qrow + lrow][32 + quad * 8];

    float m_r[4], l_r[4];
    f32x4 oacc[4] = {};
#pragma unroll
    for (int r = 0; r < 4; ++r) { m_r[r] = -1e20f; l_r[r] = 0.f; }

    for (int c = 0; c < NCH; ++c) {
        const int cur = c & 1;
        const int j0  = jstart + c * 64;

        // ---- issue chunk c+1 global loads (latency hidden under compute) --
        if (c + 1 < NCH) {
            const int j0n = jstart + (c + 1) * 64;
#pragma unroll
            for (int e = 0; e < 2; ++e) {
                int j = j0n + sjj[e];
                kr[e] = make_uint4(0, 0, 0, 0);
                vr[e] = make_uint4(0, 0, 0, 0);
                if (j >= 0 && j < SEQ) {
                    kr[e] = *(const uint4*)(k + ibase + (size_t)j * QKVS + sd0[e]);
                    vr[e] = *(const uint4*)(v + ibase + (size_t)j * QKVS + sd0[e]);
                }
            }
        }

        // ---- QK^T: 4 kt tiles of 16 keys, masked + scaled -----------------
        float p[4][4];   // [kt][r]
#pragma unroll
        for (int kt = 0; kt < 4; ++kt) {
            const int krow = kt * 16;
            bf16x8 b0 = *(const bf16x8*)&kv[cur][krow + lrow][quad * 8];
            bf16x8 b1 = *(const bf16x8*)&kv[cur][krow + lrow][32 + quad * 8];
            f32x4 acc = {};
            acc = __builtin_amdgcn_mfma_f32_16x16x32_bf16(a0, b0, acc, 0, 0, 0);
            acc = __builtin_amdgcn_mfma_f32_16x16x32_bf16(a1, b1, acc, 0, 0, 0);
            const int jg = j0 + krow + lrow;
#pragma unroll
            for (int r = 0; r < 4; ++r) {
                const int ig = i0 + qrow + quad * 4 + r;
                bool ok = (jg >= 0) && (jg < SEQ) &&
                          (jg >= ig - HW) && (jg <= ig + HW);
                p[kt][r] = ok ? acc[r] * SCALE : -1e30f;
            }
        }

        // ---- online softmax (per query row; reduce over 16-lane group) ----
#pragma unroll
        for (int r = 0; r < 4; ++r) {
            float cm = fmaxf(fmaxf(p[0][r], p[1][r]), fmaxf(p[2][r], p[3][r]));
#pragma unroll
            for (int off = 8; off; off >>= 1) cm = fmaxf(cm, __shfl_xor(cm, off));
            const float mn = fmaxf(m_r[r], cm);
            const float f  = __expf(m_r[r] - mn);
            m_r[r] = mn;
            float cs = 0.f;
#pragma unroll
            for (int kt = 0; kt < 4; ++kt) {
                float e = __expf(p[kt][r] - mn);
                p[kt][r] = e;
                cs += e;
            }
#pragma unroll
            for (int off = 8; off; off >>= 1) cs += __shfl_xor(cs, off);
            l_r[r] = l_r[r] * f + cs;
#pragma unroll
            for (int nt = 0; nt < 4; ++nt) oacc[nt][r] *= f;
        }

        // ---- P tile to sc (own wave's rows only) --------------------------
#pragma unroll
        for (int kt = 0; kt < 4; ++kt)
#pragma unroll
            for (int r = 0; r < 4; ++r)
                sc[qrow + quad * 4 + r][kt * 16 + lrow] = f2bu(p[kt][r]);

        // ---- PV: O[q][dh] += P . V^T --------------------------------------
        bf16x8 pa0 = *(const bf16x8*)&sc[qrow + lrow][quad * 8];
        bf16x8 pa1 = *(const bf16x8*)&sc[qrow + lrow][32 + quad * 8];
#pragma unroll
        for (int nt = 0; nt < 4; ++nt) {
            const int dh  = nt * 16 + lrow;
            const int rsw = (dh >> 3) & 7;
            bf16x8 b0 = *(const bf16x8*)&vt[cur][dh][((quad)     ^ rsw) * 8];
            bf16x8 b1 = *(const bf16x8*)&vt[cur][dh][((quad + 4) ^ rsw) * 8];
            oacc[nt] = __builtin_amdgcn_mfma_f32_16x16x32_bf16(pa0, b0, oacc[nt], 0, 0, 0);
            oacc[nt] = __builtin_amdgcn_mfma_f32_16x16x32_bf16(pa1, b1, oacc[nt], 0, 0, 0);
        }

        // ---- write chunk c+1 regs to buf[cur^1] ---------------------------
        if (c + 1 < NCH) {
            const int nxt = cur ^ 1;
#pragma unroll
            for (int e = 0; e < 2; ++e) {
                *(uint4*)&kv[nxt][sjj[e]][sd0[e]] = kr[e];
                const ushort* u = (const ushort*)&vr[e];
#pragma unroll
                for (int x = 0; x < 8; ++x) {
                    int dh  = sd0[e] + x;
                    int blk = ((sjj[e] >> 3) ^ (dh >> 3)) & 7;
                    vt[nxt][dh][blk * 8 + (sjj[e] & 7)] = u[x];
                }
            }
        }
        __syncthreads();   // single barrier: publishes buf[nxt], drains buf[cur]
    }

    // ---- write O: col(dh) = nt*16 + lrow, row(q) = qrow + quad*4 + r ------
#pragma unroll
    for (int r = 0; r < 4; ++r) {
        const float inv = 1.f / l_r[r];
        const int qi = i0 + qrow + quad * 4 + r;
#pragma unroll
        for (int nt = 0; nt < 4; ++nt)
            o[obase + (size_t)qi * DM + nt * 16 + lrow] = f2bu(oacc[nt][r] * inv);
    }
}

// ---------------------------------------------------------------------------
// Residual + LayerNorm, 4 rows per 256-thr block (1 wave/row). bf16 in;
// bf16 out or fp32 (final).
// ---------------------------------------------------------------------------
__global__ __launch_bounds__(256) void add_ln(
    const ushort* __restrict__ xa, const ushort* __restrict__ yb,
    const float* __restrict__ g, const float* __restrict__ be,
    ushort* __restrict__ ob, float* __restrict__ of, int fin)
{
    const int r = blockIdx.x * 4 + (threadIdx.x >> 6);
    const int t = threadIdx.x & 63;
    const size_t off = (size_t)r * DM;
    float sv[12];
    float s1 = 0.f, s2 = 0.f;
#pragma unroll
    for (int ii = 0; ii < 12; ++ii) {
        float vv = bu2f(xa[off + t + 64 * ii]) + bu2f(yb[off + t + 64 * ii]);
        sv[ii] = vv; s1 += vv; s2 += vv * vv;
    }
#pragma unroll
    for (int o2 = 32; o2; o2 >>= 1) {
        s1 += __shfl_xor(s1, o2);
        s2 += __shfl_xor(s2, o2);
    }
    const float mean = s1 * (1.f / 768.f);
    const float rstd = rsqrtf(s2 * (1.f / 768.f) - mean * mean + EPSF);
#pragma unroll
    for (int ii = 0; ii < 12; ++ii) {
        const int c = t + 64 * ii;
        float v = (sv[ii] - mean) * rstd * g[c] + be[c];
        if (fin) of[off + c] = v;
        else     ob[off + c] = f2bu(v);
    }
}

// ---------------------------------------------------------------------------
// Host orchestration.
// ---------------------------------------------------------------------------
extern "C" void kernel_launch(void* const* d_in, const int* in_sizes, int n_in,
                              void* d_out, int out_size, void* d_ws, size_t ws_size,
                              hipStream_t stream) {
    (void)in_sizes; (void)n_in; (void)out_size; (void)ws_size;
    const float* src = (const float*)d_in[0];
    const float* qw  = (const float*)d_in[1];
    const float* qb  = (const float*)d_in[2];
    const float* kw  = (const float*)d_in[3];
    const float* kb  = (const float*)d_in[4];
    const float* vw  = (const float*)d_in[5];
    const float* vb  = (const float*)d_in[6];
    const float* ow  = (const float*)d_in[7];
    const float* ob  = (const float*)d_in[8];
    const float* w1  = (const float*)d_in[9];
    const float* b1  = (const float*)d_in[10];
    const float* w2  = (const float*)d_in[11];
    const float* b2  = (const float*)d_in[12];
    const float* g1  = (const float*)d_in[13];
    const float* be1 = (const float*)d_in[14];
    const float* g2  = (const float*)d_in[15];
    const float* be2 = (const float*)d_in[16];

    const size_t A    = (size_t)MR * DM;         // 3,145,728
    const size_t WD1  = (size_t)DM * DM;         // 589,824  (per layer)
    const size_t WQKV = (size_t)3 * DM * DM;     // 1,769,472 (per layer)
    const size_t WF1  = (size_t)DFF * DM;        // 2,359,296 (per layer)
    const size_t WF   = (size_t)NL * WF1;        // 4,718,592

    float*  bcat = (float*)d_ws;                 // NL * 2304 fp32
    ushort* p    = (ushort*)(bcat + (size_t)NL * QKVS);
    ushort* qkvwB = p; p += (size_t)NL * WQKV;
    ushort* owB   = p; p += (size_t)NL * WD1;
    ushort* w1B   = p; p += WF;
    ushort* w2B   = p; p += WF;
    ushort* xb    = p; p += A;
    ushort* qkvB  = p; p += 3 * A;
    ushort* oB    = p; p += A;
    ushort* yB    = p; p += A;
    ushort* h1    = p; p += A;
    ushort* ffh   = p;                            // MR*DFF = 12.58M elems

    // split-K fp32 partials: alias the dead-at-FF2 region qkvB..yB
    // (3A+A+A = 5A ushorts = 31.45 MB >= 2*MR*DM*4B = 25.17 MB)
    float* part = (float*)qkvB;

    // bias concat (device-to-device, async on stream — graph-capture safe)
    for (int l = 0; l < NL; ++l) {
        hipMemcpyAsync(bcat + (size_t)l * QKVS + 0,    qb + (size_t)l * DM,
                       DM * sizeof(float), hipMemcpyDeviceToDevice, stream);
        hipMemcpyAsync(bcat + (size_t)l * QKVS + DM,   kb + (size_t)l * DM,
                       DM * sizeof(float), hipMemcpyDeviceToDevice, stream);
        hipMemcpyAsync(bcat + (size_t)l * QKVS + 2*DM, vb + (size_t)l * DM,
                       DM * sizeof(float), hipMemcpyDeviceToDevice, stream);
    }

    // weight + src conversion (all sizes divisible by 1024)
    for (int l = 0; l < NL; ++l) {
        cvt<<<(int)(WD1 / 1024), 256, 0, stream>>>(
            qw + (size_t)l * WD1, qkvwB + (size_t)l * WQKV + 0,     (int)WD1);
        cvt<<<(int)(WD1 / 1024), 256, 0, stream>>>(
            kw + (size_t)l * WD1, qkvwB + (size_t)l * WQKV + WD1,   (int)WD1);
        cvt<<<(int)(WD1 / 1024), 256, 0, stream>>>(
            vw + (size_t)l * WD1, qkvwB + (size_t)l * WQKV + 2*WD1, (int)WD1);
    }
    cvt<<<(int)(NL * WD1 / 1024), 256, 0, stream>>>(ow, owB, (int)(NL * WD1));
    cvt<<<(int)(WF / 1024), 256, 0, stream>>>(w1, w1B, (int)WF);
    cvt<<<(int)(WF / 1024), 256, 0, stream>>>(w2, w2B, (int)WF);
    cvt<<<(int)(A  / 1024), 256, 0, stream>>>(src, xb, (int)A);

    const dim3 gQKV(QKVS / 128, MR / 128);      // (18, 32)  576 blocks
    const dim3 gO(DM / 128, MR / 64);           // (6, 64)   384 blocks
    const dim3 gF1(DFF / 128, MR / 128);        // (24, 32)  768 blocks
    const dim3 gF2(DM / 128, MR / 64, 2);       // (6, 64, 2) 768 blocks
    const dim3 gA(SEQ / QT, NHD, BATCH);        // (32, 12, 2) 768 blocks

    for (int l = 0; l < NL; ++l) {
        const size_t bD = (size_t)l * DM;
        const size_t bF = (size_t)l * DFF;

        gemm128<<<gQKV, 256, 0, stream>>>(xb, qkvwB + (size_t)l * WQKV,
                                          bcat + (size_t)l * QKVS, qkvB,
                                          MR, QKVS, DM, 0);
        attn<<<gA, 256, 0, stream>>>(qkvB, qkvB + DM, qkvB + 2 * DM, oB);
        gemm64<<<gO, 256, 0, stream>>>(oB, owB + (size_t)l * WD1, ob + bD, yB,
                                       nullptr, MR, DM, DM, DM, 0);
        add_ln<<<MR / 4, 256, 0, stream>>>(xb, yB, g1 + bD, be1 + bD,
                                           h1, nullptr, 0);
        gemm128<<<gF1, 256, 0, stream>>>(h1, w1B + (size_t)l * WF1, b1 + bF, ffh,
                                         MR, DFF, DM, 1);
        // FF2 split-K: K=3072 -> 2 chunks of 1536; fp32 partials + reduce
        gemm64<<<gF2, 256, 0, stream>>>(ffh, w2B + (size_t)l * WF1, nullptr,
                                        nullptr, part, MR, DM, DFF / 2, DFF, 0);
        red_sk<<<(int)(A / 1024), 256, 0, stream>>>(part, b2 + bD, xb);
        if (l == NL - 1)
            add_ln<<<MR / 4, 256, 0, stream>>>(h1, xb, g2 + bD, be2 + bD,
                                               nullptr, (float*)d_out, 1);
        else
            add_ln<<<MR / 4, 256, 0, stream>>>(h1, xb, g2 + bD, be2 + bD,
                                               xb, nullptr, 0);
    }
}

// Round 6
// 477.462 us; speedup vs baseline: 3.6224x; 1.0437x over previous
//
#include <hip/hip_runtime.h>
#include <math.h>

// Problem constants
#define BATCH 2
#define SEQ   2048
#define DM    768
#define NHD   12
#define NL    2
#define DFF   3072
#define DH    64
#define HW    256            // WIN // 2
#define MR    (BATCH*SEQ)    // 4096
#define EPSF  1e-5f
#define SCALE 0.125f         // DH^-0.5
#define QKVS  2304           // fused qkv activation row stride

typedef __attribute__((ext_vector_type(8))) __bf16 bf16x8;
typedef __attribute__((ext_vector_type(4))) float  f32x4;

__device__ __forceinline__ ushort f2bu(float f) {
    union { __bf16 h; ushort u; } c;
    c.h = (__bf16)f;
    return c.u;
}
__device__ __forceinline__ float bu2f(ushort u) {
    union { uint u; float f; } c;
    c.u = ((uint)u) << 16;
    return c.f;
}

// async global->LDS, 16B per lane. LDS dest must be linear: uniform base +
// lane*16 within each wave (learn_hip m104).
__device__ __forceinline__ void gload16(const ushort* g, ushort* l) {
    __builtin_amdgcn_global_load_lds(
        (const __attribute__((address_space(1))) void*)g,
        (__attribute__((address_space(3))) void*)l, 16, 0, 0);
}

// XCD-aware chunked block remap (T1, m157/m192): consecutive logical tiles
// (which share operand panels) land on the SAME XCD's L2. Requires
// nwg % 8 == 0 (all swizzled grids here: 576/384/768). Pure permutation.
__device__ __forceinline__ void xcd_swz(int& bx, int& by, int& bz) {
    const int gx = gridDim.x, gy = gridDim.y;
    const int nwg = gx * gy * gridDim.z;
    int lin = bx + gx * (by + gy * bz);
    lin = (lin & 7) * (nwg >> 3) + (lin >> 3);
    bx = lin % gx;
    int rest = lin / gx;
    by = rest % gy;
    bz = rest / gy;
}

// ---------------------------------------------------------------------------
// fp32 -> bf16 cast, 4 elems/thread (n divisible by 1024)
// ---------------------------------------------------------------------------
__global__ __launch_bounds__(256) void cvt(const float* __restrict__ in,
                                           ushort* __restrict__ out, int n)
{
    int i = (blockIdx.x * 256 + threadIdx.x) * 4;
    if (i >= n) return;
    float4 v = *(const float4*)(in + i);
    ushort4 o;
    o.x = f2bu(v.x); o.y = f2bu(v.y); o.z = f2bu(v.z); o.w = f2bu(v.w);
    *(ushort4*)(out + i) = o;
}

// ---------------------------------------------------------------------------
// MFMA GEMM, 128x128 tile, BK=32, 256 thr = 4 waves (2x2), wave = 64x64 via
// 4x4 mfma_f32_16x16x32_bf16 fragments.
// PREFETCH DOUBLE-BUFFER (T3 minimum-2-phase): issue next K-step's
// global_load_lds BEFORE this step's ds_read+MFMA; ONE vmcnt(0)+barrier per
// K-step (compiler emits the drain at __syncthreads). Load latency hides
// under the MFMA phase.
//   WAR: iter t+1 stages buf[cur(t)]; reads of buf[cur(t)] end before iter-t
//        barrier, stage issues after it.
//   RAW: iter-t stage of buf[nxt] drains at iter-t barrier (vmcnt0); iter
//        t+1 reads after it.
// Fragment layouts (learn_hip m89/m91, HW-verified).
// ---------------------------------------------------------------------------
__global__ __launch_bounds__(256) void gemm128(
    const ushort* __restrict__ A, const ushort* __restrict__ W,
    const float* __restrict__ bias, ushort* __restrict__ C,
    int M, int N, int K, int relu)
{
    __shared__ ushort As[2][128 * 32];
    __shared__ ushort Ws[2][128 * 32];

    int bxi = blockIdx.x, byi = blockIdx.y, bzi = blockIdx.z;
    xcd_swz(bxi, byi, bzi);

    const int t  = threadIdx.x;
    const int bm = byi * 128;
    const int bn = bxi * 128;

    const int w    = t >> 6;
    const int lane = t & 63;
    const int quad = lane >> 4;
    const int lrow = lane & 15;
    const int wm   = (w >> 1) * 64;
    const int wn   = (w & 1) * 64;

    const int srow = t >> 2;          // 0..63 (e=0), +64 for e=1
    const int scol = (t & 3) * 8;
    const ushort* ag = A + (size_t)(bm + srow) * K + scol;
    const ushort* wg = W + (size_t)(bn + srow) * K + scol;

    f32x4 acc[4][4] = {};

    // prologue: stage K-step 0 into buf 0
    gload16(ag,                  &As[0][t * 8]);
    gload16(ag + (size_t)64 * K, &As[0][2048 + t * 8]);
    gload16(wg,                  &Ws[0][t * 8]);
    gload16(wg + (size_t)64 * K, &Ws[0][2048 + t * 8]);
    __syncthreads();

    int cur = 0;
    for (int k0 = 0; k0 < K; k0 += 32) {
        const int nxt = cur ^ 1;
        if (k0 + 32 < K) {   // issue next-step loads; they fly during MFMA
            gload16(ag + k0 + 32,                  &As[nxt][t * 8]);
            gload16(ag + (size_t)64 * K + k0 + 32, &As[nxt][2048 + t * 8]);
            gload16(wg + k0 + 32,                  &Ws[nxt][t * 8]);
            gload16(wg + (size_t)64 * K + k0 + 32, &Ws[nxt][2048 + t * 8]);
        }

        bf16x8 af[4], bfr[4];
#pragma unroll
        for (int i = 0; i < 4; ++i)
            af[i] = *(const bf16x8*)&As[cur][(wm + i * 16 + lrow) * 32 + quad * 8];
#pragma unroll
        for (int j = 0; j < 4; ++j)
            bfr[j] = *(const bf16x8*)&Ws[cur][(wn + j * 16 + lrow) * 32 + quad * 8];

#pragma unroll
        for (int i = 0; i < 4; ++i)
#pragma unroll
            for (int j = 0; j < 4; ++j)
                acc[i][j] = __builtin_amdgcn_mfma_f32_16x16x32_bf16(
                    af[i], bfr[j], acc[i][j], 0, 0, 0);
        __syncthreads();   // single drain: publishes buf[nxt], retires buf[cur]
        cur = nxt;
    }

#pragma unroll
    for (int j = 0; j < 4; ++j) {
        const int col = bn + wn + j * 16 + lrow;
        const float bv = bias[col];
#pragma unroll
        for (int i = 0; i < 4; ++i) {
            const int rb = bm + wm + i * 16 + quad * 4;
#pragma unroll
            for (int r = 0; r < 4; ++r) {
                float vv = acc[i][j][r] + bv;
                if (relu) vv = fmaxf(vv, 0.f);
                C[(size_t)(rb + r) * N + col] = f2bu(vv);
            }
        }
    }
}

// ---------------------------------------------------------------------------
// MFMA GEMM, BM=64 x BN=128, BK=32, 4 waves (2x2), wave = 32x64 via 2x4
// fragments. Same prefetch double-buffer as gemm128. Optional split-K:
// z = K-chunk; if gridDim.z > 1, write fp32 partials to part[z*M*N + ...];
// else bf16 + bias (+relu). Kc = chunk length, ldk = full-K row stride.
// ---------------------------------------------------------------------------
__global__ __launch_bounds__(256) void gemm64(
    const ushort* __restrict__ A, const ushort* __restrict__ W,
    const float* __restrict__ bias, ushort* __restrict__ C,
    float* __restrict__ part, int M, int N, int Kc, int ldk, int relu)
{
    __shared__ ushort As[2][64 * 32];
    __shared__ ushort Ws[2][128 * 32];

    int bxi = blockIdx.x, byi = blockIdx.y, bzi = blockIdx.z;
    xcd_swz(bxi, byi, bzi);

    const int t  = threadIdx.x;
    const int bm = byi * 64;
    const int bn = bxi * 128;
    const int z  = bzi;
    const int kbase = z * Kc;

    const int w    = t >> 6;
    const int lane = t & 63;
    const int quad = lane >> 4;
    const int lrow = lane & 15;
    const int wm   = (w >> 1) * 32;
    const int wn   = (w & 1) * 64;

    const int srow = t >> 2;          // 0..63
    const int scol = (t & 3) * 8;
    const ushort* ag = A + (size_t)(bm + srow) * ldk + kbase + scol;
    const ushort* wg = W + (size_t)(bn + srow) * ldk + kbase + scol;

    f32x4 acc[2][4] = {};

    // prologue: stage K-step 0 into buf 0
    gload16(ag,                    &As[0][t * 8]);
    gload16(wg,                    &Ws[0][t * 8]);
    gload16(wg + (size_t)64 * ldk, &Ws[0][2048 + t * 8]);
    __syncthreads();

    int cur = 0;
    for (int k0 = 0; k0 < Kc; k0 += 32) {
        const int nxt = cur ^ 1;
        if (k0 + 32 < Kc) {
            gload16(ag + k0 + 32,                    &As[nxt][t * 8]);
            gload16(wg + k0 + 32,                    &Ws[nxt][t * 8]);
            gload16(wg + (size_t)64 * ldk + k0 + 32, &Ws[nxt][2048 + t * 8]);
        }

        bf16x8 af[2], bfr[4];
#pragma unroll
        for (int i = 0; i < 2; ++i)
            af[i] = *(const bf16x8*)&As[cur][(wm + i * 16 + lrow) * 32 + quad * 8];
#pragma unroll
        for (int j = 0; j < 4; ++j)
            bfr[j] = *(const bf16x8*)&Ws[cur][(wn + j * 16 + lrow) * 32 + quad * 8];

#pragma unroll
        for (int i = 0; i < 2; ++i)
#pragma unroll
            for (int j = 0; j < 4; ++j)
                acc[i][j] = __builtin_amdgcn_mfma_f32_16x16x32_bf16(
                    af[i], bfr[j], acc[i][j], 0, 0, 0);
        __syncthreads();
        cur = nxt;
    }

    if (gridDim.z > 1) {
        float* po = part + (size_t)z * M * N;
#pragma unroll
        for (int j = 0; j < 4; ++j) {
            const int col = bn + wn + j * 16 + lrow;
#pragma unroll
            for (int i = 0; i < 2; ++i) {
                const int rb = bm + wm + i * 16 + quad * 4;
#pragma unroll
                for (int r = 0; r < 4; ++r)
                    po[(size_t)(rb + r) * N + col] = acc[i][j][r];
            }
        }
    } else {
#pragma unroll
        for (int j = 0; j < 4; ++j) {
            const int col = bn + wn + j * 16 + lrow;
            const float bv = bias[col];
#pragma unroll
            for (int i = 0; i < 2; ++i) {
                const int rb = bm + wm + i * 16 + quad * 4;
#pragma unroll
                for (int r = 0; r < 4; ++r) {
                    float vv = acc[i][j][r] + bv;
                    if (relu) vv = fmaxf(vv, 0.f);
                    C[(size_t)(rb + r) * N + col] = f2bu(vv);
                }
            }
        }
    }
}

// ---------------------------------------------------------------------------
// Banded attention, fused flash-style single pass, DOUBLE-BUFFERED (T14):
// Block = (64 queries, head, batch), 256 thr = 4 waves; wave w owns query
// rows [w*16, w*16+16). One barrier per 64-key chunk. (Unchanged from R5.)
// ---------------------------------------------------------------------------
#define QT  64
#define NCH 9    // union window 64+512 = 576 keys
#define KP  72   // LDS pitch in bf16 (144 B rows: 16B-aligned, 2-way max)

__global__ __launch_bounds__(256) void attn(
    const ushort* __restrict__ q, const ushort* __restrict__ k,
    const ushort* __restrict__ v, ushort* __restrict__ o)
{
    __shared__ ushort kv[2][64][KP];   // K chunk [key][dh]
    __shared__ ushort vt[2][64][KP];   // V^T chunk [dh][key], XOR-swizzled
    __shared__ ushort sc[QT][KP];      // Q staging, then per-chunk P tiles

    int bxi = blockIdx.x, byi = blockIdx.y, bzi = blockIdx.z;
    xcd_swz(bxi, byi, bzi);            // seq-neighbors share KV -> same XCD

    const int t    = threadIdx.x;
    const int i0   = bxi * QT;
    const int h    = byi;
    const int b    = bzi;
    const size_t ibase = (size_t)b * SEQ * QKVS + (size_t)h * DH;  // q/k/v
    const size_t obase = (size_t)b * SEQ * DM   + (size_t)h * DH;  // o

    const int w    = t >> 6;
    const int lane = t & 63;
    const int quad = lane >> 4;
    const int lrow = lane & 15;
    const int qrow = w * 16;            // wave's 16 query rows

    const int jstart = i0 - HW;

    // per-thread staging coords (constant across chunks)
    const int sjj[2] = { t >> 3, (t + 256) >> 3 };
    const int sd0[2] = { (t & 7) * 8, (t & 7) * 8 };

    // ---- stage Q into sc + load chunk 0 into regs -------------------------
#pragma unroll
    for (int e = 0; e < 2; ++e) {
        int idx = t + 256 * e;
        int qi = idx >> 3, d0 = (idx & 7) * 8;
        uint4 raw = *(const uint4*)(q + ibase + (size_t)(i0 + qi) * QKVS + d0);
        *(uint4*)&sc[qi][d0] = raw;
    }
    uint4 kr[2], vr[2];
#pragma unroll
    for (int e = 0; e < 2; ++e) {
        int j = jstart + sjj[e];
        kr[e] = make_uint4(0, 0, 0, 0);
        vr[e] = make_uint4(0, 0, 0, 0);
        if (j >= 0 && j < SEQ) {
            kr[e] = *(const uint4*)(k + ibase + (size_t)j * QKVS + sd0[e]);
            vr[e] = *(const uint4*)(v + ibase + (size_t)j * QKVS + sd0[e]);
        }
    }
    // write chunk 0 to buf 0 (no conflict with sc)
#pragma unroll
    for (int e = 0; e < 2; ++e) {
        *(uint4*)&kv[0][sjj[e]][sd0[e]] = kr[e];
        const ushort* u = (const ushort*)&vr[e];
#pragma unroll
        for (int x = 0; x < 8; ++x) {
            int dh  = sd0[e] + x;
            int blk = ((sjj[e] >> 3) ^ (dh >> 3)) & 7;
            vt[0][dh][blk * 8 + (sjj[e] & 7)] = u[x];
        }
    }
    __syncthreads();   // publish sc (Q) and buf0

    // Q fragments (chunk-invariant); after this each wave touches only its
    // own sc rows, so sc is safely reused for P tiles.
    const bf16x8 a0 = *(const bf16x8*)&sc[qrow + lrow][quad * 8];
    const bf16x8 a1 = *(const bf16x8*)&sc[qrow + lrow][32 + quad * 8];

    float m_r[4], l_r[4];
    f32x4 oacc[4] = {};
#pragma unroll
    for (int r = 0; r < 4; ++r) { m_r[r] = -1e20f; l_r[r] = 0.f; }

    for (int c = 0; c < NCH; ++c) {
        const int cur = c & 1;
        const int j0  = jstart + c * 64;

        // ---- issue chunk c+1 global loads (latency hidden under compute) --
        if (c + 1 < NCH) {
            const int j0n = jstart + (c + 1) * 64;
#pragma unroll
            for (int e = 0; e < 2; ++e) {
                int j = j0n + sjj[e];
                kr[e] = make_uint4(0, 0, 0, 0);
                vr[e] = make_uint4(0, 0, 0, 0);
                if (j >= 0 && j < SEQ) {
                    kr[e] = *(const uint4*)(k + ibase + (size_t)j * QKVS + sd0[e]);
                    vr[e] = *(const uint4*)(v + ibase + (size_t)j * QKVS + sd0[e]);
                }
            }
        }

        // ---- QK^T: 4 kt tiles of 16 keys, masked + scaled -----------------
        float p[4][4];   // [kt][r]
#pragma unroll
        for (int kt = 0; kt < 4; ++kt) {
            const int krow = kt * 16;
            bf16x8 b0 = *(const bf16x8*)&kv[cur][krow + lrow][quad * 8];
            bf16x8 b1 = *(const bf16x8*)&kv[cur][krow + lrow][32 + quad * 8];
            f32x4 acc = {};
            acc = __builtin_amdgcn_mfma_f32_16x16x32_bf16(a0, b0, acc, 0, 0, 0);
            acc = __builtin_amdgcn_mfma_f32_16x16x32_bf16(a1, b1, acc, 0, 0, 0);
            const int jg = j0 + krow + lrow;
#pragma unroll
            for (int r = 0; r < 4; ++r) {
                const int ig = i0 + qrow + quad * 4 + r;
                bool ok = (jg >= 0) && (jg < SEQ) &&
                          (jg >= ig - HW) && (jg <= ig + HW);
                p[kt][r] = ok ? acc[r] * SCALE : -1e30f;
            }
        }

        // ---- online softmax (per query row; reduce over 16-lane group) ----
#pragma unroll
        for (int r = 0; r < 4; ++r) {
            float cm = fmaxf(fmaxf(p[0][r], p[1][r]), fmaxf(p[2][r], p[3][r]));
#pragma unroll
            for (int off = 8; off; off >>= 1) cm = fmaxf(cm, __shfl_xor(cm, off));
            const float mn = fmaxf(m_r[r], cm);
            const float f  = __expf(m_r[r] - mn);
            m_r[r] = mn;
            float cs = 0.f;
#pragma unroll
            for (int kt = 0; kt < 4; ++kt) {
                float e = __expf(p[kt][r] - mn);
                p[kt][r] = e;
                cs += e;
            }
#pragma unroll
            for (int off = 8; off; off >>= 1) cs += __shfl_xor(cs, off);
            l_r[r] = l_r[r] * f + cs;
#pragma unroll
            for (int nt = 0; nt < 4; ++nt) oacc[nt][r] *= f;
        }

        // ---- P tile to sc (own wave's rows only) --------------------------
#pragma unroll
        for (int kt = 0; kt < 4; ++kt)
#pragma unroll
            for (int r = 0; r < 4; ++r)
                sc[qrow + quad * 4 + r][kt * 16 + lrow] = f2bu(p[kt][r]);

        // ---- PV: O[q][dh] += P . V^T --------------------------------------
        bf16x8 pa0 = *(const bf16x8*)&sc[qrow + lrow][quad * 8];
        bf16x8 pa1 = *(const bf16x8*)&sc[qrow + lrow][32 + quad * 8];
#pragma unroll
        for (int nt = 0; nt < 4; ++nt) {
            const int dh  = nt * 16 + lrow;
            const int rsw = (dh >> 3) & 7;
            bf16x8 b0 = *(const bf16x8*)&vt[cur][dh][((quad)     ^ rsw) * 8];
            bf16x8 b1 = *(const bf16x8*)&vt[cur][dh][((quad + 4) ^ rsw) * 8];
            oacc[nt] = __builtin_amdgcn_mfma_f32_16x16x32_bf16(pa0, b0, oacc[nt], 0, 0, 0);
            oacc[nt] = __builtin_amdgcn_mfma_f32_16x16x32_bf16(pa1, b1, oacc[nt], 0, 0, 0);
        }

        // ---- write chunk c+1 regs to buf[cur^1] ---------------------------
        if (c + 1 < NCH) {
            const int nxt = cur ^ 1;
#pragma unroll
            for (int e = 0; e < 2; ++e) {
                *(uint4*)&kv[nxt][sjj[e]][sd0[e]] = kr[e];
                const ushort* u = (const ushort*)&vr[e];
#pragma unroll
                for (int x = 0; x < 8; ++x) {
                    int dh  = sd0[e] + x;
                    int blk = ((sjj[e] >> 3) ^ (dh >> 3)) & 7;
                    vt[nxt][dh][blk * 8 + (sjj[e] & 7)] = u[x];
                }
            }
        }
        __syncthreads();   // single barrier: publishes buf[nxt], drains buf[cur]
    }

    // ---- write O: col(dh) = nt*16 + lrow, row(q) = qrow + quad*4 + r ------
#pragma unroll
    for (int r = 0; r < 4; ++r) {
        const float inv = 1.f / l_r[r];
        const int qi = i0 + qrow + quad * 4 + r;
#pragma unroll
        for (int nt = 0; nt < 4; ++nt)
            o[obase + (size_t)qi * DM + nt * 16 + lrow] = f2bu(oacc[nt][r] * inv);
    }
}

// ---------------------------------------------------------------------------
// Residual + LayerNorm, 4 rows per 256-thr block (1 wave/row). bf16 in;
// bf16 out or fp32 (final).
// ---------------------------------------------------------------------------
__global__ __launch_bounds__(256) void add_ln(
    const ushort* __restrict__ xa, const ushort* __restrict__ yb,
    const float* __restrict__ g, const float* __restrict__ be,
    ushort* __restrict__ ob, float* __restrict__ of, int fin)
{
    const int r = blockIdx.x * 4 + (threadIdx.x >> 6);
    const int t = threadIdx.x & 63;
    const size_t off = (size_t)r * DM;
    float sv[12];
    float s1 = 0.f, s2 = 0.f;
#pragma unroll
    for (int ii = 0; ii < 12; ++ii) {
        float vv = bu2f(xa[off + t + 64 * ii]) + bu2f(yb[off + t + 64 * ii]);
        sv[ii] = vv; s1 += vv; s2 += vv * vv;
    }
#pragma unroll
    for (int o2 = 32; o2; o2 >>= 1) {
        s1 += __shfl_xor(s1, o2);
        s2 += __shfl_xor(s2, o2);
    }
    const float mean = s1 * (1.f / 768.f);
    const float rstd = rsqrtf(s2 * (1.f / 768.f) - mean * mean + EPSF);
#pragma unroll
    for (int ii = 0; ii < 12; ++ii) {
        const int c = t + 64 * ii;
        float v = (sv[ii] - mean) * rstd * g[c] + be[c];
        if (fin) of[off + c] = v;
        else     ob[off + c] = f2bu(v);
    }
}

// ---------------------------------------------------------------------------
// Fused split-K reduce + residual + LayerNorm (FF2 tail):
// row = LN(h1 + (p0 + p1 + b2)), fp32 end-to-end (one fewer bf16 round).
// 4 rows per 256-thr block (1 wave/row). Replaces red_sk + add_ln pair.
// ---------------------------------------------------------------------------
__global__ __launch_bounds__(256) void add_ln_sk(
    const ushort* __restrict__ xa, const float* __restrict__ pp,
    const float* __restrict__ bias, const float* __restrict__ g,
    const float* __restrict__ be,
    ushort* __restrict__ ob, float* __restrict__ of, int fin)
{
    const int r = blockIdx.x * 4 + (threadIdx.x >> 6);
    const int t = threadIdx.x & 63;
    const size_t off = (size_t)r * DM;
    float sv[12];
    float s1 = 0.f, s2 = 0.f;
#pragma unroll
    for (int ii = 0; ii < 12; ++ii) {
        const int c = t + 64 * ii;
        float vv = bu2f(xa[off + c]) + pp[off + c]
                 + pp[(size_t)MR * DM + off + c] + bias[c];
        sv[ii] = vv; s1 += vv; s2 += vv * vv;
    }
#pragma unroll
    for (int o2 = 32; o2; o2 >>= 1) {
        s1 += __shfl_xor(s1, o2);
        s2 += __shfl_xor(s2, o2);
    }
    const float mean = s1 * (1.f / 768.f);
    const float rstd = rsqrtf(s2 * (1.f / 768.f) - mean * mean + EPSF);
#pragma unroll
    for (int ii = 0; ii < 12; ++ii) {
        const int c = t + 64 * ii;
        float v = (sv[ii] - mean) * rstd * g[c] + be[c];
        if (fin) of[off + c] = v;
        else     ob[off + c] = f2bu(v);
    }
}

// ---------------------------------------------------------------------------
// Host orchestration.
// ---------------------------------------------------------------------------
extern "C" void kernel_launch(void* const* d_in, const int* in_sizes, int n_in,
                              void* d_out, int out_size, void* d_ws, size_t ws_size,
                              hipStream_t stream) {
    (void)in_sizes; (void)n_in; (void)out_size; (void)ws_size;
    const float* src = (const float*)d_in[0];
    const float* qw  = (const float*)d_in[1];
    const float* qb  = (const float*)d_in[2];
    const float* kw  = (const float*)d_in[3];
    const float* kb  = (const float*)d_in[4];
    const float* vw  = (const float*)d_in[5];
    const float* vb  = (const float*)d_in[6];
    const float* ow  = (const float*)d_in[7];
    const float* ob  = (const float*)d_in[8];
    const float* w1  = (const float*)d_in[9];
    const float* b1  = (const float*)d_in[10];
    const float* w2  = (const float*)d_in[11];
    const float* b2  = (const float*)d_in[12];
    const float* g1  = (const float*)d_in[13];
    const float* be1 = (const float*)d_in[14];
    const float* g2  = (const float*)d_in[15];
    const float* be2 = (const float*)d_in[16];

    const size_t A    = (size_t)MR * DM;         // 3,145,728
    const size_t WD1  = (size_t)DM * DM;         // 589,824  (per layer)
    const size_t WQKV = (size_t)3 * DM * DM;     // 1,769,472 (per layer)
    const size_t WF1  = (size_t)DFF * DM;        // 2,359,296 (per layer)
    const size_t WF   = (size_t)NL * WF1;        // 4,718,592

    float*  bcat = (float*)d_ws;                 // NL * 2304 fp32
    ushort* p    = (ushort*)(bcat + (size_t)NL * QKVS);
    ushort* qkvwB = p; p += (size_t)NL * WQKV;
    ushort* owB   = p; p += (size_t)NL * WD1;
    ushort* w1B   = p; p += WF;
    ushort* w2B   = p; p += WF;
    ushort* xb    = p; p += A;
    ushort* qkvB  = p; p += 3 * A;
    ushort* oB    = p; p += A;
    ushort* yB    = p; p += A;
    ushort* h1    = p; p += A;
    ushort* ffh   = p;                            // MR*DFF = 12.58M elems

    // split-K fp32 partials: alias the dead-at-FF2 region qkvB..yB
    // (3A+A+A = 5A ushorts = 31.45 MB >= 2*MR*DM*4B = 25.17 MB)
    float* part = (float*)qkvB;

    // bias concat (device-to-device, async on stream — graph-capture safe)
    for (int l = 0; l < NL; ++l) {
        hipMemcpyAsync(bcat + (size_t)l * QKVS + 0,    qb + (size_t)l * DM,
                       DM * sizeof(float), hipMemcpyDeviceToDevice, stream);
        hipMemcpyAsync(bcat + (size_t)l * QKVS + DM,   kb + (size_t)l * DM,
                       DM * sizeof(float), hipMemcpyDeviceToDevice, stream);
        hipMemcpyAsync(bcat + (size_t)l * QKVS + 2*DM, vb + (size_t)l * DM,
                       DM * sizeof(float), hipMemcpyDeviceToDevice, stream);
    }

    // weight + src conversion (all sizes divisible by 1024)
    for (int l = 0; l < NL; ++l) {
        cvt<<<(int)(WD1 / 1024), 256, 0, stream>>>(
            qw + (size_t)l * WD1, qkvwB + (size_t)l * WQKV + 0,     (int)WD1);
        cvt<<<(int)(WD1 / 1024), 256, 0, stream>>>(
            kw + (size_t)l * WD1, qkvwB + (size_t)l * WQKV + WD1,   (int)WD1);
        cvt<<<(int)(WD1 / 1024), 256, 0, stream>>>(
            vw + (size_t)l * WD1, qkvwB + (size_t)l * WQKV + 2*WD1, (int)WD1);
    }
    cvt<<<(int)(NL * WD1 / 1024), 256, 0, stream>>>(ow, owB, (int)(NL * WD1));
    cvt<<<(int)(WF / 1024), 256, 0, stream>>>(w1, w1B, (int)WF);
    cvt<<<(int)(WF / 1024), 256, 0, stream>>>(w2, w2B, (int)WF);
    cvt<<<(int)(A  / 1024), 256, 0, stream>>>(src, xb, (int)A);

    const dim3 gQKV(QKVS / 128, MR / 128);      // (18, 32)  576 blocks
    const dim3 gO(DM / 128, MR / 64);           // (6, 64)   384 blocks
    const dim3 gF1(DFF / 128, MR / 128);        // (24, 32)  768 blocks
    const dim3 gF2(DM / 128, MR / 64, 2);       // (6, 64, 2) 768 blocks
    const dim3 gA(SEQ / QT, NHD, BATCH);        // (32, 12, 2) 768 blocks

    for (int l = 0; l < NL; ++l) {
        const size_t bD = (size_t)l * DM;
        const size_t bF = (size_t)l * DFF;

        gemm128<<<gQKV, 256, 0, stream>>>(xb, qkvwB + (size_t)l * WQKV,
                                          bcat + (size_t)l * QKVS, qkvB,
                                          MR, QKVS, DM, 0);
        attn<<<gA, 256, 0, stream>>>(qkvB, qkvB + DM, qkvB + 2 * DM, oB);
        gemm64<<<gO, 256, 0, stream>>>(oB, owB + (size_t)l * WD1, ob + bD, yB,
                                       nullptr, MR, DM, DM, DM, 0);
        add_ln<<<MR / 4, 256, 0, stream>>>(xb, yB, g1 + bD, be1 + bD,
                                           h1, nullptr, 0);
        gemm128<<<gF1, 256, 0, stream>>>(h1, w1B + (size_t)l * WF1, b1 + bF, ffh,
                                         MR, DFF, DM, 1);
        // FF2 split-K: K=3072 -> 2 chunks of 1536; fp32 partials, then
        // fused reduce+bias+residual+LN (fp32 end-to-end)
        gemm64<<<gF2, 256, 0, stream>>>(ffh, w2B + (size_t)l * WF1, nullptr,
                                        nullptr, part, MR, DM, DFF / 2, DFF, 0);
        if (l == NL - 1)
            add_ln_sk<<<MR / 4, 256, 0, stream>>>(h1, part, b2 + bD,
                                                  g2 + bD, be2 + bD,
                                                  nullptr, (float*)d_out, 1);
        else
            add_ln_sk<<<MR / 4, 256, 0, stream>>>(h1, part, b2 + bD,
                                                  g2 + bD, be2 + bD,
                                                  xb, nullptr, 0);
    }
}